// Round 2
// baseline (657.185 us; speedup 1.0000x reference)
//
#include <hip/hip_runtime.h>
#include <hip/hip_bf16.h>

#define BB 4
#define NN 128
#define NDIM 256
#define EDIM 128
#define CDIM 256
#define NH 8
#define DH 32

__device__ __forceinline__ float lrelu(float x){ return fmaxf(x, 0.1f*x); }

// cond = conds @ Wc + bc  -> (B, 1024) fp32
__global__ void k_cond(const float* conds, const float* Wc, const float* bc, float* cond){
  __shared__ float c[CDIM];
  int b = blockIdx.x, t = threadIdx.x;
  c[t] = conds[(size_t)b*CDIM + t];
  __syncthreads();
  for (int i = 0; i < 4; i++){
    int j = t + i*256;
    float acc = bc[j];
    for (int kk = 0; kk < CDIM; kk++) acc += c[kk]*Wc[(size_t)kk*1024 + j];
    cond[b*1024 + j] = acc;
  }
}

// out = lrelu( LN(x) * (1+cond[mo..]) + cond[ao..] ), per (b,n) row
__global__ void k_film(const float* x, const float* cond, int mo, int ao, float* out){
  int row = blockIdx.x, t = threadIdx.x;
  int b = row / NN;
  float v = x[(size_t)row*NDIM + t];
  __shared__ float red[256];
  red[t] = v; __syncthreads();
  for (int s = 128; s > 0; s >>= 1){ if (t < s) red[t] += red[t+s]; __syncthreads(); }
  float m = red[0] * (1.f/NDIM);
  __syncthreads();
  float d0 = v - m;
  red[t] = d0*d0; __syncthreads();
  for (int s = 128; s > 0; s >>= 1){ if (t < s) red[t] += red[t+s]; __syncthreads(); }
  float inv = rsqrtf(red[0] * (1.f/NDIM) + 1e-5f);
  float y = d0*inv*(1.f + cond[b*1024 + mo + t]) + cond[b*1024 + ao + t];
  out[(size_t)row*NDIM + t] = lrelu(y);
}

// qkv = n_in @ Wqkv + bqkv -> (B*N, 768) fp32
__global__ void k_qkv(const float* n_in, const float* Wqkv, const float* bqkv, float* qkv){
  __shared__ float a[NDIM];
  int row = blockIdx.x, t = threadIdx.x;
  a[t] = n_in[(size_t)row*NDIM + t];
  __syncthreads();
  for (int i = 0; i < 3; i++){
    int j = t + i*256;
    float acc = bqkv[j];
    for (int kk = 0; kk < NDIM; kk++) acc += a[kk]*Wqkv[(size_t)kk*768 + j];
    qkv[(size_t)row*768 + j] = acc;
  }
}

// Fused edge hot path, 16 edge-pairs per block (same b,qi):
// e_in=lrelu(LN(edges)); ss=e_in@Wss+bss; ne=a5*(1+scale)+shift;
// logits=sum_d(ne)/sqrt(D); edges1 = edges + lrelu(ne)@Weo + beo
__global__ __launch_bounds__(256) void k_edge_main(
    const float* edges, const float* qkv,
    const float* Wss, const float* bss,
    const float* Weo, const float* beo,
    float* edges1, float* logits){
  __shared__ __align__(16) float raw[16][EDIM];
  __shared__ __align__(16) float a[16][EDIM];
  __shared__ __align__(16) float lne[16][NDIM];
  __shared__ float mrow[16], irow[16];
  int t = threadIdx.x;
  int p0 = blockIdx.x * 16;
  int b  = p0 >> 14;
  int qi = (p0 >> 7) & 127;
  int ki0 = p0 & 127;

  const float4* e4 = (const float4*)(edges + (size_t)p0*EDIM);
  float4* raw4 = (float4*)raw;
  raw4[t]       = e4[t];
  raw4[t + 256] = e4[t + 256];
  __syncthreads();
  if (t < 16){
    float s = 0;
    for (int c = 0; c < EDIM; c++) s += raw[t][c];
    float m = s * (1.f/EDIM);
    float v = 0;
    for (int c = 0; c < EDIM; c++){ float d = raw[t][c] - m; v += d*d; }
    mrow[t] = m; irow[t] = rsqrtf(v * (1.f/EDIM) + 1e-5f);
  }
  __syncthreads();
  for (int i = 0; i < 8; i++){
    int idx = t + i*256; int r = idx >> 7, c = idx & 127;
    a[r][c] = lrelu((raw[r][c] - mrow[r]) * irow[r]);
  }
  __syncthreads();

  // ss GEMM: thread t owns shift col t and scale col t+256, rows 0..15
  float accS[16], accC[16];
  float bs0 = bss[t], bs1 = bss[t + 256];
  #pragma unroll
  for (int r = 0; r < 16; r++){ accS[r] = bs0; accC[r] = bs1; }
  for (int k4 = 0; k4 < EDIM/4; k4++){
    int kk = k4*4;
    float w0a = Wss[(size_t)(kk+0)*512 + t], w0b = Wss[(size_t)(kk+0)*512 + t + 256];
    float w1a = Wss[(size_t)(kk+1)*512 + t], w1b = Wss[(size_t)(kk+1)*512 + t + 256];
    float w2a = Wss[(size_t)(kk+2)*512 + t], w2b = Wss[(size_t)(kk+2)*512 + t + 256];
    float w3a = Wss[(size_t)(kk+3)*512 + t], w3b = Wss[(size_t)(kk+3)*512 + t + 256];
    #pragma unroll
    for (int r = 0; r < 16; r++){
      float4 av = ((const float4*)a[r])[k4];
      accS[r] += av.x*w0a + av.y*w1a + av.z*w2a + av.w*w3a;
      accC[r] += av.x*w0b + av.y*w1b + av.z*w2b + av.w*w3b;
    }
  }

  float qv = qkv[(size_t)(b*NN + qi)*768 + t];
  const float isd = 0.17677669529663687f; // 1/sqrt(32)
  for (int r = 0; r < 16; r++){
    float kv = qkv[(size_t)(b*NN + ki0 + r)*768 + 256 + t];
    float a5 = qv * kv;
    float ne = a5*(1.f + accC[r]) + accS[r];
    float s = ne;
    for (int off = 16; off > 0; off >>= 1) s += __shfl_down(s, off, 32);
    if ((t & 31) == 0)
      logits[((size_t)(b*NH + (t >> 5))*NN + qi)*NN + ki0 + r] = s * isd;
    lne[r][t] = lrelu(ne);
  }
  __syncthreads();

  // delta_edges GEMM + residual
  int j = t & 127;
  int rg = (t >> 7) * 8;
  float acc2[8];
  float bj = beo[j];
  #pragma unroll
  for (int rr = 0; rr < 8; rr++) acc2[rr] = bj;
  for (int k4 = 0; k4 < NDIM/4; k4++){
    int kk = k4*4;
    float w0 = Weo[(size_t)(kk+0)*EDIM + j];
    float w1 = Weo[(size_t)(kk+1)*EDIM + j];
    float w2 = Weo[(size_t)(kk+2)*EDIM + j];
    float w3 = Weo[(size_t)(kk+3)*EDIM + j];
    #pragma unroll
    for (int rr = 0; rr < 8; rr++){
      float4 lv = ((const float4*)lne[rg + rr])[k4];
      acc2[rr] += lv.x*w0 + lv.y*w1 + lv.z*w2 + lv.w*w3;
    }
  }
  for (int rr = 0; rr < 8; rr++){
    int r = rg + rr;
    edges1[(size_t)(p0 + r)*EDIM + j] = raw[r][j] + acc2[rr];
  }
}

// softmax over q axis (axis=2): per (b,h), each thread owns one ki column
__global__ void k_softmax(float* logits){
  int bh = blockIdx.x, ki = threadIdx.x;
  float* base = logits + (size_t)bh*NN*NN + ki;
  float mx = -3.4e38f;
  for (int qi = 0; qi < NN; qi++) mx = fmaxf(mx, base[(size_t)qi*NN]);
  float s = 0.f;
  for (int qi = 0; qi < NN; qi++) s += expf(base[(size_t)qi*NN] - mx);
  float inv = 1.f/s;
  for (int qi = 0; qi < NN; qi++) base[(size_t)qi*NN] = expf(base[(size_t)qi*NN] - mx)*inv;
}

// wv[b,q,h,d] = sum_k attn[b,h,q,k] * v[b,k,h,d]
__global__ void k_wv(const float* attn, const float* qkv, float* wv){
  __shared__ float at[NH][NN];
  int row = blockIdx.x; int b = row / NN, qi = row % NN;
  int t = threadIdx.x;
  for (int i = 0; i < 4; i++){
    int idx = t + i*256; int h = idx >> 7, ki = idx & 127;
    at[h][ki] = attn[((size_t)(b*NH + h)*NN + qi)*NN + ki];
  }
  __syncthreads();
  int h = t >> 5;
  float acc = 0.f;
  for (int ki = 0; ki < NN; ki++)
    acc += at[h][ki] * qkv[(size_t)(b*NN + ki)*768 + 512 + t];
  wv[(size_t)row*NDIM + t] = acc;
}

// nodes1 = nodes + wv @ Wno + bno
__global__ void k_dnodes(const float* nodes, const float* wv,
                         const float* Wno, const float* bno, float* nodes1){
  __shared__ float a[NDIM];
  int row = blockIdx.x, t = threadIdx.x;
  a[t] = wv[(size_t)row*NDIM + t];
  __syncthreads();
  float acc = bno[t];
  for (int kk = 0; kk < NDIM; kk++) acc += a[kk]*Wno[(size_t)kk*NDIM + t];
  nodes1[(size_t)row*NDIM + t] = nodes[(size_t)row*NDIM + t] + acc;
}

// hidden = lrelu(n_out @ Wn1 + bn1)
__global__ void k_mlp1(const float* n_out, const float* Wn1, const float* bn1, float* hidden){
  __shared__ float a[NDIM];
  int row = blockIdx.x, t = threadIdx.x;
  a[t] = n_out[(size_t)row*NDIM + t];
  __syncthreads();
  for (int i = 0; i < 4; i++){
    int j = t + i*256;
    float acc = bn1[j];
    for (int kk = 0; kk < NDIM; kk++) acc += a[kk]*Wn1[(size_t)kk*1024 + j];
    hidden[(size_t)row*1024 + j] = lrelu(acc);
  }
}

// out_nodes = nodes1 + hidden @ Wn2 + bn2  (fp32 out)
__global__ void k_mlp2(const float* nodes1, const float* hidden,
                       const float* Wn2, const float* bn2, float* out){
  __shared__ float a[1024];
  int row = blockIdx.x, t = threadIdx.x;
  for (int i = 0; i < 4; i++) a[t + i*256] = hidden[(size_t)row*1024 + t + i*256];
  __syncthreads();
  float acc = bn2[t];
  for (int kk = 0; kk < 1024; kk++) acc += a[kk]*Wn2[(size_t)kk*NDIM + t];
  out[(size_t)row*NDIM + t] = nodes1[(size_t)row*NDIM + t] + acc;
}

// edges_final = edges1 + lrelu(lrelu(LN(edges1))@We1+be1)@We2 + be2  (in-place fp32)
__global__ __launch_bounds__(256) void k_edge_mlp(float* e,
    const float* We1, const float* be1,
    const float* We2, const float* be2){
  __shared__ __align__(16) float raw[32][EDIM];
  __shared__ __align__(16) float a1[32][EDIM];
  __shared__ __align__(16) float hb[32][EDIM];
  __shared__ float mrow[32], irow[32];
  int t = threadIdx.x;
  size_t p0 = (size_t)blockIdx.x * 32;
  const float4* e4 = (const float4*)(e + p0*EDIM);
  float4* raw4 = (float4*)raw;
  for (int i = 0; i < 4; i++) raw4[t + i*256] = e4[t + i*256];
  __syncthreads();
  if (t < 32){
    float s = 0; for (int c = 0; c < EDIM; c++) s += raw[t][c];
    float m = s * (1.f/EDIM), v = 0;
    for (int c = 0; c < EDIM; c++){ float d = raw[t][c] - m; v += d*d; }
    mrow[t] = m; irow[t] = rsqrtf(v * (1.f/EDIM) + 1e-5f);
  }
  __syncthreads();
  for (int i = 0; i < 16; i++){
    int idx = t + i*256; int r = idx >> 7, c = idx & 127;
    a1[r][c] = lrelu((raw[r][c] - mrow[r]) * irow[r]);
  }
  __syncthreads();
  int j = t & 127;
  int rg = (t >> 7) * 16;
  float acc[16];
  float b1 = be1[j];
  #pragma unroll
  for (int rr = 0; rr < 16; rr++) acc[rr] = b1;
  for (int k4 = 0; k4 < EDIM/4; k4++){
    int kk = k4*4;
    float w0 = We1[(size_t)(kk+0)*EDIM + j];
    float w1 = We1[(size_t)(kk+1)*EDIM + j];
    float w2 = We1[(size_t)(kk+2)*EDIM + j];
    float w3 = We1[(size_t)(kk+3)*EDIM + j];
    #pragma unroll
    for (int rr = 0; rr < 16; rr++){
      float4 av = ((const float4*)a1[rg + rr])[k4];
      acc[rr] += av.x*w0 + av.y*w1 + av.z*w2 + av.w*w3;
    }
  }
  for (int rr = 0; rr < 16; rr++){ hb[rg + rr][j] = lrelu(acc[rr]); }
  __syncthreads();
  float b2 = be2[j];
  #pragma unroll
  for (int rr = 0; rr < 16; rr++) acc[rr] = b2;
  for (int k4 = 0; k4 < EDIM/4; k4++){
    int kk = k4*4;
    float w0 = We2[(size_t)(kk+0)*EDIM + j];
    float w1 = We2[(size_t)(kk+1)*EDIM + j];
    float w2 = We2[(size_t)(kk+2)*EDIM + j];
    float w3 = We2[(size_t)(kk+3)*EDIM + j];
    #pragma unroll
    for (int rr = 0; rr < 16; rr++){
      float4 hv = ((const float4*)hb[rg + rr])[k4];
      acc[rr] += hv.x*w0 + hv.y*w1 + hv.z*w2 + hv.w*w3;
    }
  }
  for (int rr = 0; rr < 16; rr++){
    int r = rg + rr;
    e[(p0 + r)*EDIM + j] = raw[r][j] + acc[rr];
  }
}

extern "C" void kernel_launch(void* const* d_in, const int* in_sizes, int n_inp,
                              void* d_out, int out_size, void* d_ws, size_t ws_size,
                              hipStream_t stream){
  const float* nodes = (const float*)d_in[0];
  const float* edges = (const float*)d_in[1];
  const float* conds = (const float*)d_in[2];
  const float* Wc   = (const float*)d_in[3];
  const float* bc   = (const float*)d_in[4];
  const float* Wqkv = (const float*)d_in[5];
  const float* bqkv = (const float*)d_in[6];
  const float* Wss  = (const float*)d_in[7];
  const float* bss  = (const float*)d_in[8];
  const float* Wno  = (const float*)d_in[9];
  const float* bno  = (const float*)d_in[10];
  const float* Weo  = (const float*)d_in[11];
  const float* beo  = (const float*)d_in[12];
  const float* Wn1  = (const float*)d_in[13];
  const float* bn1  = (const float*)d_in[14];
  const float* Wn2  = (const float*)d_in[15];
  const float* bn2  = (const float*)d_in[16];
  const float* We1  = (const float*)d_in[17];
  const float* be1  = (const float*)d_in[18];
  const float* We2  = (const float*)d_in[19];
  const float* be2  = (const float*)d_in[20];

  float* ws     = (float*)d_ws;
  float* cond   = ws;                 // 4096
  float* n_in   = cond   + 4096;      // 131072
  float* qkvb   = n_in   + 131072;    // 393216
  float* logits = qkvb   + 393216;    // 524288
  float* wv     = logits + 524288;    // 131072
  float* nodes1 = wv     + 131072;    // 131072
  float* n_out  = nodes1 + 131072;    // 131072
  float* hidden = n_out  + 131072;    // 524288

  float* out_nodes = (float*)d_out;
  float* out_edges = out_nodes + 131072;

  k_cond<<<BB, 256, 0, stream>>>(conds, Wc, bc, cond);
  k_film<<<BB*NN, 256, 0, stream>>>(nodes, cond, 0, 256, n_in);
  k_qkv<<<BB*NN, 256, 0, stream>>>(n_in, Wqkv, bqkv, qkvb);
  k_edge_main<<<BB*NN*NN/16, 256, 0, stream>>>(edges, qkvb, Wss, bss, Weo, beo, out_edges, logits);
  k_softmax<<<BB*NH, 128, 0, stream>>>(logits);
  k_wv<<<BB*NN, 256, 0, stream>>>(logits, qkvb, wv);
  k_dnodes<<<BB*NN, 256, 0, stream>>>(nodes, wv, Wno, bno, nodes1);
  k_film<<<BB*NN, 256, 0, stream>>>(nodes1, cond, 512, 768, n_out);
  k_mlp1<<<BB*NN, 256, 0, stream>>>(n_out, Wn1, bn1, hidden);
  k_mlp2<<<BB*NN, 256, 0, stream>>>(nodes1, hidden, Wn2, bn2, out_nodes);
  k_edge_mlp<<<BB*NN*NN/32, 256, 0, stream>>>(out_edges, We1, be1, We2, be2);
}

// Round 3
// 429.419 us; speedup vs baseline: 1.5304x; 1.5304x over previous
//
#include <hip/hip_runtime.h>
#include <hip/hip_bf16.h>

#define BB 4
#define NN 128
#define NDIM 256
#define EDIM 128
#define CDIM 256
#define NH 8
#define DH 32

typedef __attribute__((ext_vector_type(8))) short short8;
typedef __attribute__((ext_vector_type(4))) float f32x4;

__device__ __forceinline__ float lrelu(float x){ return fmaxf(x, 0.1f*x); }
__device__ __forceinline__ unsigned short f2b(float x){
  __hip_bfloat16 h = __float2bfloat16(x);
  return *reinterpret_cast<unsigned short*>(&h);
}

// ---------- weight prep: transpose + bf16-convert edge weights into ws ----------
// wbf layout (ushort): WssT[512][128] | WeoT[128][256] | We1T[128][128] | We2T[128][128]
__global__ void k_prep(const float* Wss, const float* Weo, const float* We1, const float* We2,
                       unsigned short* wbf){
  int idx = blockIdx.x*256 + threadIdx.x;        // 0..131071
  if (idx < 65536){            // WssT[n][k] = Wss[k][n], k<128, n<512
    int n = idx >> 7, k = idx & 127;
    wbf[idx] = f2b(Wss[(size_t)k*512 + n]);
  } else if (idx < 98304){     // WeoT[n][k] = Weo[k][n], k<256, n<128
    int i = idx - 65536; int n = i >> 8, k = i & 255;
    wbf[idx] = f2b(Weo[(size_t)k*128 + n]);
  } else if (idx < 114688){    // We1T
    int i = idx - 98304; int n = i >> 7, k = i & 127;
    wbf[idx] = f2b(We1[(size_t)k*128 + n]);
  } else {                     // We2T
    int i = idx - 114688; int n = i >> 7, k = i & 127;
    wbf[idx] = f2b(We2[(size_t)k*128 + n]);
  }
}

// cond = conds @ Wc + bc  -> (B, 1024) fp32
__global__ void k_cond(const float* conds, const float* Wc, const float* bc, float* cond){
  __shared__ float c[CDIM];
  int b = blockIdx.x, t = threadIdx.x;
  c[t] = conds[(size_t)b*CDIM + t];
  __syncthreads();
  for (int i = 0; i < 4; i++){
    int j = t + i*256;
    float acc = bc[j];
    for (int kk = 0; kk < CDIM; kk++) acc += c[kk]*Wc[(size_t)kk*1024 + j];
    cond[b*1024 + j] = acc;
  }
}

// out = lrelu( LN(x) * (1+cond[mo..]) + cond[ao..] ), per (b,n) row
__global__ void k_film(const float* x, const float* cond, int mo, int ao, float* out){
  int row = blockIdx.x, t = threadIdx.x;
  int b = row / NN;
  float v = x[(size_t)row*NDIM + t];
  __shared__ float red[256];
  red[t] = v; __syncthreads();
  for (int s = 128; s > 0; s >>= 1){ if (t < s) red[t] += red[t+s]; __syncthreads(); }
  float m = red[0] * (1.f/NDIM);
  __syncthreads();
  float d0 = v - m;
  red[t] = d0*d0; __syncthreads();
  for (int s = 128; s > 0; s >>= 1){ if (t < s) red[t] += red[t+s]; __syncthreads(); }
  float inv = rsqrtf(red[0] * (1.f/NDIM) + 1e-5f);
  float y = d0*inv*(1.f + cond[b*1024 + mo + t]) + cond[b*1024 + ao + t];
  out[(size_t)row*NDIM + t] = lrelu(y);
}

// qkv = n_in @ Wqkv + bqkv -> (B*N, 768) fp32
__global__ void k_qkv(const float* n_in, const float* Wqkv, const float* bqkv, float* qkv){
  __shared__ float a[NDIM];
  int row = blockIdx.x, t = threadIdx.x;
  a[t] = n_in[(size_t)row*NDIM + t];
  __syncthreads();
  for (int i = 0; i < 3; i++){
    int j = t + i*256;
    float acc = bqkv[j];
    for (int kk = 0; kk < NDIM; kk++) acc += a[kk]*Wqkv[(size_t)kk*768 + j];
    qkv[(size_t)row*768 + j] = acc;
  }
}

// ---------------- MFMA fused edge main ----------------
// 32 edge-pairs per block (same b,qi). LN -> bf16 a -> ss GEMM (MFMA, B from WssT)
// -> ne elementwise + logits (shfl reduce) -> lne bf16 -> Weo GEMM (MFMA) + residual.
#define ASTR 152   // ushort stride for K=128 bf16 tiles (16B aligned rows, low conflict)
#define LSTR 280   // ushort stride for K=256 lne tile
#define RSTR 132   // fp32 stride for raw edges

__global__ __launch_bounds__(256) void k_edge_main(
    const float* __restrict__ edges, const float* __restrict__ qkv,
    const unsigned short* __restrict__ WssT, const float* __restrict__ bss,
    const unsigned short* __restrict__ WeoT, const float* __restrict__ beo,
    float* __restrict__ edges1, float* __restrict__ logits){
  __shared__ __align__(16) float raw[32*RSTR];
  __shared__ __align__(16) unsigned short abuf[32*ASTR];
  __shared__ __align__(16) unsigned short lbuf[32*LSTR];
  __shared__ float qvs[256];
  __shared__ float psum[256], psq[256];
  __shared__ float mrow[32], irow[32];

  int t = threadIdx.x;
  int p0 = blockIdx.x * 32;
  int b  = p0 >> 14;
  int qi = (p0 >> 7) & 127;
  int ki0 = p0 & 127;
  int l = t & 63, w = t >> 6;
  int l15 = l & 15, q = l >> 4;

  // stage raw edges (32x128 fp32) via float4
  {
    const float4* src = (const float4*)(edges + (size_t)p0*EDIM);
    #pragma unroll
    for (int i = 0; i < 4; i++){
      int f = t + i*256; int r = f >> 5, c4 = f & 31;
      *(float4*)(raw + r*RSTR + c4*4) = src[f];
    }
    qvs[t] = qkv[(size_t)(b*NN + qi)*768 + t];
  }
  __syncthreads();
  // LN stats: row = t>>3, part = t&7
  {
    int r = t >> 3, p = t & 7;
    float s = 0.f, s2 = 0.f;
    #pragma unroll
    for (int i = 0; i < 16; i++){
      float v = raw[r*RSTR + p + 8*i];
      s += v; s2 += v*v;
    }
    psum[t] = s; psq[t] = s2;
  }
  __syncthreads();
  if (t < 32){
    float s = 0.f, s2 = 0.f;
    #pragma unroll
    for (int i = 0; i < 8; i++){ s += psum[t*8+i]; s2 += psq[t*8+i]; }
    float m = s * (1.f/EDIM);
    mrow[t] = m;
    irow[t] = rsqrtf(s2*(1.f/EDIM) - m*m + 1e-5f);
  }
  __syncthreads();
  // a = bf16(lrelu(LN))
  #pragma unroll
  for (int i = 0; i < 16; i++){
    int f = t + i*256; int r = f >> 7, c = f & 127;
    float x = (raw[r*RSTR + c] - mrow[r]) * irow[r];
    abuf[r*ASTR + c] = f2b(lrelu(x));
  }
  __syncthreads();

  // ---- GEMM1: (32x128)@(128x512) + elementwise + logits ----
  const float isd = 0.17677669529663687f; // 1/sqrt(32)
  {
    int mb = (w & 1) * 16;
    int nbase = (w >> 1) * 128;   // ne-column base for this wave (0 or 128)
    short8 af[4];
    #pragma unroll
    for (int k = 0; k < 4; k++)
      af[k] = *(const short8*)(abuf + (mb + l15)*ASTR + k*32 + q*8);
    float hsPrev[4];
    #pragma unroll
    for (int tt = 0; tt < 8; tt++){
      int c = nbase + tt*16 + l15;            // ne column 0..255
      const unsigned short* bs = WssT + (size_t)c*128 + q*8;
      const unsigned short* bc = WssT + (size_t)(c+256)*128 + q*8;
      f32x4 aS = {0.f,0.f,0.f,0.f}, aC = {0.f,0.f,0.f,0.f};
      #pragma unroll
      for (int k = 0; k < 4; k++){
        aS = __builtin_amdgcn_mfma_f32_16x16x32_bf16(af[k], *(const short8*)(bs + k*32), aS, 0,0,0);
        aC = __builtin_amdgcn_mfma_f32_16x16x32_bf16(af[k], *(const short8*)(bc + k*32), aC, 0,0,0);
      }
      float bS = bss[c], bC = bss[256 + c];
      float qv = qvs[c];
      float hs[4];
      #pragma unroll
      for (int r = 0; r < 4; r++){
        int row = mb + q*4 + r;
        float kv = qkv[(size_t)(b*NN + ki0 + row)*768 + 256 + c];
        float a5 = qv * kv;
        float ne = a5*(1.f + (aC[r] + bC)) + (aS[r] + bS);
        lbuf[row*LSTR + c] = f2b(lrelu(ne));
        float v = ne;
        v += __shfl_xor(v, 1); v += __shfl_xor(v, 2);
        v += __shfl_xor(v, 4); v += __shfl_xor(v, 8);
        hs[r] = v;
      }
      if (tt & 1){
        if (l15 == 0){
          int h = (nbase + tt*16) >> 5;
          #pragma unroll
          for (int r = 0; r < 4; r++){
            int ki = ki0 + mb + q*4 + r;
            logits[((size_t)(b*NH + h)*NN + qi)*NN + ki] = (hsPrev[r] + hs[r]) * isd;
          }
        }
      } else {
        #pragma unroll
        for (int r = 0; r < 4; r++) hsPrev[r] = hs[r];
      }
    }
  }
  __syncthreads();

  // ---- GEMM2: lne(32x256)@(256x128) + residual ----
  {
    int mb = (w & 1) * 16;
    short8 lf[8];
    #pragma unroll
    for (int k = 0; k < 8; k++)
      lf[k] = *(const short8*)(lbuf + (mb + l15)*LSTR + k*32 + q*8);
    #pragma unroll
    for (int tt = 0; tt < 4; tt++){
      int col = (w >> 1)*64 + tt*16 + l15;
      const unsigned short* bp = WeoT + (size_t)col*256 + q*8;
      f32x4 acc = {0.f,0.f,0.f,0.f};
      #pragma unroll
      for (int k = 0; k < 8; k++)
        acc = __builtin_amdgcn_mfma_f32_16x16x32_bf16(lf[k], *(const short8*)(bp + k*32), acc, 0,0,0);
      float bb = beo[col];
      #pragma unroll
      for (int r = 0; r < 4; r++){
        int row = mb + q*4 + r;
        edges1[(size_t)(p0 + row)*EDIM + col] = raw[row*RSTR + col] + acc[r] + bb;
      }
    }
  }
}

// softmax over q axis (axis=2): per (b,h), each thread owns one ki column
__global__ void k_softmax(float* logits){
  int bh = blockIdx.x, ki = threadIdx.x;
  float* base = logits + (size_t)bh*NN*NN + ki;
  float mx = -3.4e38f;
  #pragma unroll 8
  for (int qi = 0; qi < NN; qi++) mx = fmaxf(mx, base[(size_t)qi*NN]);
  float s = 0.f;
  #pragma unroll 8
  for (int qi = 0; qi < NN; qi++){ float e = expf(base[(size_t)qi*NN] - mx); base[(size_t)qi*NN] = e; s += e; }
  float inv = 1.f/s;
  #pragma unroll 8
  for (int qi = 0; qi < NN; qi++) base[(size_t)qi*NN] *= inv;
}

// wv[b,q,h,d] = sum_k attn[b,h,q,k] * v[b,k,h,d]
__global__ void k_wv(const float* attn, const float* qkv, float* wv){
  __shared__ float at[NH][NN];
  int row = blockIdx.x; int b = row / NN, qi = row % NN;
  int t = threadIdx.x;
  for (int i = 0; i < 4; i++){
    int idx = t + i*256; int h = idx >> 7, ki = idx & 127;
    at[h][ki] = attn[((size_t)(b*NH + h)*NN + qi)*NN + ki];
  }
  __syncthreads();
  int h = t >> 5;
  float acc = 0.f;
  for (int ki = 0; ki < NN; ki++)
    acc += at[h][ki] * qkv[(size_t)(b*NN + ki)*768 + 512 + t];
  wv[(size_t)row*NDIM + t] = acc;
}

// nodes1 = nodes + wv @ Wno + bno
__global__ void k_dnodes(const float* nodes, const float* wv,
                         const float* Wno, const float* bno, float* nodes1){
  __shared__ float a[NDIM];
  int row = blockIdx.x, t = threadIdx.x;
  a[t] = wv[(size_t)row*NDIM + t];
  __syncthreads();
  float acc = bno[t];
  for (int kk = 0; kk < NDIM; kk++) acc += a[kk]*Wno[(size_t)kk*NDIM + t];
  nodes1[(size_t)row*NDIM + t] = nodes[(size_t)row*NDIM + t] + acc;
}

// hidden = lrelu(n_out @ Wn1 + bn1)
__global__ void k_mlp1(const float* n_out, const float* Wn1, const float* bn1, float* hidden){
  __shared__ float a[NDIM];
  int row = blockIdx.x, t = threadIdx.x;
  a[t] = n_out[(size_t)row*NDIM + t];
  __syncthreads();
  for (int i = 0; i < 4; i++){
    int j = t + i*256;
    float acc = bn1[j];
    for (int kk = 0; kk < NDIM; kk++) acc += a[kk]*Wn1[(size_t)kk*1024 + j];
    hidden[(size_t)row*1024 + j] = lrelu(acc);
  }
}

// out_nodes = nodes1 + hidden @ Wn2 + bn2  (fp32 out)
__global__ void k_mlp2(const float* nodes1, const float* hidden,
                       const float* Wn2, const float* bn2, float* out){
  __shared__ float a[1024];
  int row = blockIdx.x, t = threadIdx.x;
  for (int i = 0; i < 4; i++) a[t + i*256] = hidden[(size_t)row*1024 + t + i*256];
  __syncthreads();
  float acc = bn2[t];
  for (int kk = 0; kk < 1024; kk++) acc += a[kk]*Wn2[(size_t)kk*NDIM + t];
  out[(size_t)row*NDIM + t] = nodes1[(size_t)row*NDIM + t] + acc;
}

// ---------------- MFMA fused edge MLP ----------------
// e += lrelu(lrelu(LN(e))@We1+be1)@We2 + be2, 32 rows/block, in-place fp32
__global__ __launch_bounds__(256) void k_edge_mlp(float* __restrict__ e,
    const unsigned short* __restrict__ We1T, const float* __restrict__ be1,
    const unsigned short* __restrict__ We2T, const float* __restrict__ be2){
  __shared__ __align__(16) float raw[32*RSTR];
  __shared__ __align__(16) unsigned short abuf[32*ASTR];
  __shared__ __align__(16) unsigned short hbuf[32*ASTR];
  __shared__ float psum[256], psq[256];
  __shared__ float mrow[32], irow[32];

  int t = threadIdx.x;
  size_t p0 = (size_t)blockIdx.x * 32;
  int l = t & 63, w = t >> 6;
  int l15 = l & 15, q = l >> 4;
  int mb = (w & 1) * 16;

  {
    const float4* src = (const float4*)(e + p0*EDIM);
    #pragma unroll
    for (int i = 0; i < 4; i++){
      int f = t + i*256; int r = f >> 5, c4 = f & 31;
      *(float4*)(raw + r*RSTR + c4*4) = src[f];
    }
  }
  __syncthreads();
  {
    int r = t >> 3, p = t & 7;
    float s = 0.f, s2 = 0.f;
    #pragma unroll
    for (int i = 0; i < 16; i++){
      float v = raw[r*RSTR + p + 8*i];
      s += v; s2 += v*v;
    }
    psum[t] = s; psq[t] = s2;
  }
  __syncthreads();
  if (t < 32){
    float s = 0.f, s2 = 0.f;
    #pragma unroll
    for (int i = 0; i < 8; i++){ s += psum[t*8+i]; s2 += psq[t*8+i]; }
    float m = s * (1.f/EDIM);
    mrow[t] = m;
    irow[t] = rsqrtf(s2*(1.f/EDIM) - m*m + 1e-5f);
  }
  __syncthreads();
  #pragma unroll
  for (int i = 0; i < 16; i++){
    int f = t + i*256; int r = f >> 7, c = f & 127;
    float x = (raw[r*RSTR + c] - mrow[r]) * irow[r];
    abuf[r*ASTR + c] = f2b(lrelu(x));
  }
  __syncthreads();

  // GEMM1: a(32x128)@We1T^T -> hidden, lrelu, to hbuf
  {
    short8 af[4];
    #pragma unroll
    for (int k = 0; k < 4; k++)
      af[k] = *(const short8*)(abuf + (mb + l15)*ASTR + k*32 + q*8);
    #pragma unroll
    for (int tt = 0; tt < 4; tt++){
      int col = (w >> 1)*64 + tt*16 + l15;
      const unsigned short* bp = We1T + (size_t)col*128 + q*8;
      f32x4 acc = {0.f,0.f,0.f,0.f};
      #pragma unroll
      for (int k = 0; k < 4; k++)
        acc = __builtin_amdgcn_mfma_f32_16x16x32_bf16(af[k], *(const short8*)(bp + k*32), acc, 0,0,0);
      float bb = be1[col];
      #pragma unroll
      for (int r = 0; r < 4; r++){
        int row = mb + q*4 + r;
        hbuf[row*ASTR + col] = f2b(lrelu(acc[r] + bb));
      }
    }
  }
  __syncthreads();
  // GEMM2: h(32x128)@We2T^T + residual
  {
    short8 hf[4];
    #pragma unroll
    for (int k = 0; k < 4; k++)
      hf[k] = *(const short8*)(hbuf + (mb + l15)*ASTR + k*32 + q*8);
    #pragma unroll
    for (int tt = 0; tt < 4; tt++){
      int col = (w >> 1)*64 + tt*16 + l15;
      const unsigned short* bp = We2T + (size_t)col*128 + q*8;
      f32x4 acc = {0.f,0.f,0.f,0.f};
      #pragma unroll
      for (int k = 0; k < 4; k++)
        acc = __builtin_amdgcn_mfma_f32_16x16x32_bf16(hf[k], *(const short8*)(bp + k*32), acc, 0,0,0);
      float bb = be2[col];
      #pragma unroll
      for (int r = 0; r < 4; r++){
        int row = mb + q*4 + r;
        e[(p0 + row)*EDIM + col] = raw[row*RSTR + col] + acc[r] + bb;
      }
    }
  }
}

extern "C" void kernel_launch(void* const* d_in, const int* in_sizes, int n_inp,
                              void* d_out, int out_size, void* d_ws, size_t ws_size,
                              hipStream_t stream){
  const float* nodes = (const float*)d_in[0];
  const float* edges = (const float*)d_in[1];
  const float* conds = (const float*)d_in[2];
  const float* Wc   = (const float*)d_in[3];
  const float* bc   = (const float*)d_in[4];
  const float* Wqkv = (const float*)d_in[5];
  const float* bqkv = (const float*)d_in[6];
  const float* Wss  = (const float*)d_in[7];
  const float* bss  = (const float*)d_in[8];
  const float* Wno  = (const float*)d_in[9];
  const float* bno  = (const float*)d_in[10];
  const float* Weo  = (const float*)d_in[11];
  const float* beo  = (const float*)d_in[12];
  const float* Wn1  = (const float*)d_in[13];
  const float* bn1  = (const float*)d_in[14];
  const float* Wn2  = (const float*)d_in[15];
  const float* bn2  = (const float*)d_in[16];
  const float* We1  = (const float*)d_in[17];
  const float* be1  = (const float*)d_in[18];
  const float* We2  = (const float*)d_in[19];
  const float* be2  = (const float*)d_in[20];

  float* ws     = (float*)d_ws;
  float* cond   = ws;                 // 4096
  float* n_in   = cond   + 4096;      // 131072 (freed after k_qkv; reused for bf16 weights)
  float* qkvb   = n_in   + 131072;    // 393216
  float* logits = qkvb   + 393216;    // 524288
  float* wv     = logits + 524288;    // 131072
  float* nodes1 = wv     + 131072;    // 131072
  float* n_out  = nodes1 + 131072;    // 131072
  float* hidden = n_out  + 131072;    // 524288

  unsigned short* wbf  = (unsigned short*)n_in;  // 131072 ushorts = 256 KB (fits in n_in's 512 KB)
  unsigned short* WssT = wbf;            // 512*128
  unsigned short* WeoT = wbf + 65536;    // 128*256
  unsigned short* We1T = wbf + 98304;    // 128*128
  unsigned short* We2T = wbf + 114688;   // 128*128

  float* out_nodes = (float*)d_out;
  float* out_edges = out_nodes + 131072;

  k_cond<<<BB, 256, 0, stream>>>(conds, Wc, bc, cond);
  k_film<<<BB*NN, 256, 0, stream>>>(nodes, cond, 0, 256, n_in);
  k_qkv<<<BB*NN, 256, 0, stream>>>(n_in, Wqkv, bqkv, qkvb);
  k_prep<<<512, 256, 0, stream>>>(Wss, Weo, We1, We2, wbf);   // overwrites n_in (now dead)
  k_edge_main<<<BB*NN*NN/32, 256, 0, stream>>>(edges, qkvb, WssT, bss, WeoT, beo, out_edges, logits);
  k_softmax<<<BB*NH, 128, 0, stream>>>(logits);
  k_wv<<<BB*NN, 256, 0, stream>>>(logits, qkvb, wv);
  k_dnodes<<<BB*NN, 256, 0, stream>>>(nodes, wv, Wno, bno, nodes1);
  k_film<<<BB*NN, 256, 0, stream>>>(nodes1, cond, 512, 768, n_out);
  k_mlp1<<<BB*NN, 256, 0, stream>>>(n_out, Wn1, bn1, hidden);
  k_mlp2<<<BB*NN, 256, 0, stream>>>(nodes1, hidden, Wn2, bn2, out_nodes);
  k_edge_mlp<<<BB*NN*NN/32, 256, 0, stream>>>(out_edges, We1T, be1, We2T, be2);
}

// Round 4
// 385.633 us; speedup vs baseline: 1.7042x; 1.1135x over previous
//
#include <hip/hip_runtime.h>
#include <hip/hip_bf16.h>

#define BB 4
#define NN 128
#define NDIM 256
#define EDIM 128
#define NH 8

typedef __attribute__((ext_vector_type(8))) short short8;
typedef __attribute__((ext_vector_type(4))) float f32x4;

__device__ __forceinline__ float lrelu(float x){ return fmaxf(x, 0.1f*x); }
__device__ __forceinline__ unsigned short f2b(float x){
  __hip_bfloat16 h = __float2bfloat16(x);
  return *reinterpret_cast<unsigned short*>(&h);
}

// ---- setup: bf16-transpose edge weights (blocks 0..511) + cond GEMM (blocks 512..515) ----
// wbf (ushort): WssT[512][128] | WeoT[128][256] | We1T[128][128] | We2T[128][128]
__global__ void k_setup(const float* Wss, const float* Weo, const float* We1, const float* We2,
                        const float* conds, const float* Wc, const float* bc,
                        unsigned short* wbf, float* cond){
  int bid = blockIdx.x, t = threadIdx.x;
  if (bid < 512){
    int idx = bid*256 + t;
    if (idx < 65536){ int n = idx>>7, k = idx&127; wbf[idx] = f2b(Wss[(size_t)k*512+n]); }
    else if (idx < 98304){ int i = idx-65536; int n = i>>8, k = i&255; wbf[idx] = f2b(Weo[(size_t)k*128+n]); }
    else if (idx < 114688){ int i = idx-98304; int n = i>>7, k = i&127; wbf[idx] = f2b(We1[(size_t)k*128+n]); }
    else { int i = idx-114688; int n = i>>7, k = i&127; wbf[idx] = f2b(We2[(size_t)k*128+n]); }
  } else {
    int b = bid - 512;
    __shared__ float c[256];
    c[t] = conds[(size_t)b*256 + t];
    __syncthreads();
    for (int i = 0; i < 4; i++){
      int j = t + i*256;
      float acc = bc[j];
      for (int kk = 0; kk < 256; kk++) acc += c[kk]*Wc[(size_t)kk*1024 + j];
      cond[b*1024 + j] = acc;
    }
  }
}

// ---- film1 + qkv fused, one block per (b,n) row ----
__global__ __launch_bounds__(256) void k_nodeA(const float* __restrict__ nodes,
    const float* __restrict__ cond, const float* __restrict__ Wqkv,
    const float* __restrict__ bqkv, float* __restrict__ qkv){
  __shared__ float red[256];
  __shared__ float a[256];
  int row = blockIdx.x, t = threadIdx.x, b = row >> 7;
  float v = nodes[(size_t)row*256 + t];
  red[t] = v; __syncthreads();
  for (int s=128; s>0; s>>=1){ if (t<s) red[t]+=red[t+s]; __syncthreads(); }
  float m = red[0]*(1.f/256); __syncthreads();
  float d0 = v-m; red[t]=d0*d0; __syncthreads();
  for (int s=128; s>0; s>>=1){ if (t<s) red[t]+=red[t+s]; __syncthreads(); }
  float inv = rsqrtf(red[0]*(1.f/256)+1e-5f);
  a[t] = lrelu(d0*inv*(1.f+cond[b*1024+t]) + cond[b*1024+256+t]);
  __syncthreads();
  for (int i=0;i<3;i++){
    int j = t + i*256;
    float acc = bqkv[j];
    for (int kk=0;kk<256;kk++) acc += a[kk]*Wqkv[(size_t)kk*768+j];
    qkv[(size_t)row*768+j] = acc;
  }
}

// ---- fully fused edge path: LN->ss GEMM->ne/logitsT->Weo GEMM->LN->MLP GEMM x2 ----
#define ASTR 136   // ushort stride, K=128 tiles
#define LSTR 264   // ushort stride, K=256 lne tile

__global__ __launch_bounds__(256,4) void k_edge(
    const float* __restrict__ edges, const float* __restrict__ qkv,
    const unsigned short* __restrict__ WssT, const float* __restrict__ bss,
    const unsigned short* __restrict__ WeoT, const float* __restrict__ beo,
    const unsigned short* __restrict__ We1T, const float* __restrict__ be1,
    const unsigned short* __restrict__ We2T, const float* __restrict__ be2,
    float* __restrict__ logitsT, float* __restrict__ out_edges){
  __shared__ __align__(16) unsigned short abuf[32*ASTR];
  __shared__ __align__(16) unsigned short lbuf[32*LSTR];
  __shared__ float qvs[256];
  __shared__ float lgs[256];
  __shared__ float redS[32][2], redQ[32][2];
  __shared__ float mrow[32], irow[32];

  int t = threadIdx.x;
  int p0 = blockIdx.x * 32;
  int b  = p0 >> 14;
  int qi = (p0 >> 7) & 127;
  int ki0 = p0 & 127;
  int l = t & 63, w = t >> 6;
  int l15 = l & 15, q = l >> 4;
  int mb = (w & 1) * 16;
  int cg = w >> 1;

  // Phase 0: stage edges, LN in registers (half-wave owns a full 128-col row), write a to abuf
  {
    qvs[t] = qkv[(size_t)(b*128 + qi)*768 + t];
    const float4* src = (const float4*)(edges + (size_t)p0*128);
    int c4 = t & 31;
    int rbase = t >> 5;
    float4 ev[4];
    #pragma unroll
    for (int i=0;i<4;i++) ev[i] = src[t + i*256];
    #pragma unroll
    for (int i=0;i<4;i++){
      int r = rbase + i*8;
      float s  = ev[i].x + ev[i].y + ev[i].z + ev[i].w;
      float s2 = ev[i].x*ev[i].x + ev[i].y*ev[i].y + ev[i].z*ev[i].z + ev[i].w*ev[i].w;
      #pragma unroll
      for (int mm=1; mm<32; mm<<=1){ s += __shfl_xor(s,mm); s2 += __shfl_xor(s2,mm); }
      float m = s*(1.f/128);
      float inv = rsqrtf(s2*(1.f/128) - m*m + 1e-5f);
      ushort4 pk;
      pk.x = f2b(lrelu((ev[i].x - m)*inv));
      pk.y = f2b(lrelu((ev[i].y - m)*inv));
      pk.z = f2b(lrelu((ev[i].z - m)*inv));
      pk.w = f2b(lrelu((ev[i].w - m)*inv));
      *(ushort4*)(abuf + r*ASTR + c4*4) = pk;
    }
  }
  __syncthreads();

  // Phase 1: ss GEMM (32x128 @ 128x512) + elementwise ne + lne + head sums
  short8 af[4];
  #pragma unroll
  for (int k=0;k<4;k++) af[k] = *(const short8*)(abuf + (mb+l15)*ASTR + k*32 + q*8);
  {
    int nbase = cg*128;
    float hsPrev[4];
    #pragma unroll
    for (int tt=0; tt<8; tt++){
      int c = nbase + tt*16 + l15;
      const unsigned short* bs = WssT + (size_t)c*128 + q*8;
      const unsigned short* bcp = WssT + (size_t)(c+256)*128 + q*8;
      f32x4 aS={0.f,0.f,0.f,0.f}, aC={0.f,0.f,0.f,0.f};
      #pragma unroll
      for (int k=0;k<4;k++){
        aS = __builtin_amdgcn_mfma_f32_16x16x32_bf16(af[k], *(const short8*)(bs+k*32), aS,0,0,0);
        aC = __builtin_amdgcn_mfma_f32_16x16x32_bf16(af[k], *(const short8*)(bcp+k*32), aC,0,0,0);
      }
      float bS = bss[c], bC = bss[256+c], qv = qvs[c];
      float hs[4];
      #pragma unroll
      for (int r=0;r<4;r++){
        int row = mb + q*4 + r;
        float kv = qkv[(size_t)(b*128 + ki0 + row)*768 + 256 + c];
        float a5 = qv*kv;
        float ne = a5*(1.f + (aC[r]+bC)) + (aS[r]+bS);
        lbuf[row*LSTR + c] = f2b(lrelu(ne));
        float vv = ne;
        vv += __shfl_xor(vv,1); vv += __shfl_xor(vv,2);
        vv += __shfl_xor(vv,4); vv += __shfl_xor(vv,8);
        hs[r] = vv;
      }
      if (tt & 1){
        if (l15 == 0){
          int h = cg*4 + (tt>>1);
          #pragma unroll
          for (int r=0;r<4;r++)
            lgs[h*32 + mb + q*4 + r] = hsPrev[r] + hs[r];
        }
      } else {
        #pragma unroll
        for (int r=0;r<4;r++) hsPrev[r] = hs[r];
      }
    }
  }
  __syncthreads();
  {
    int h = t >> 5, kk = t & 31;
    logitsT[((size_t)(b*8 + h)*128 + ki0 + kk)*128 + qi] = lgs[t] * 0.17677669529663687f;
  }

  // Phase 2: Weo GEMM (32x256 @ 256x128) + residual (edges re-read from L2), LN stats of edges1
  short8 lf[8];
  #pragma unroll
  for (int k=0;k<8;k++) lf[k] = *(const short8*)(lbuf + (mb+l15)*LSTR + k*32 + q*8);
  float res[4][4];
  #pragma unroll
  for (int tt=0; tt<4; tt++){
    int col = cg*64 + tt*16 + l15;
    const unsigned short* bp = WeoT + (size_t)col*256 + q*8;
    f32x4 acc = {0.f,0.f,0.f,0.f};
    #pragma unroll
    for (int k=0;k<8;k++)
      acc = __builtin_amdgcn_mfma_f32_16x16x32_bf16(lf[k], *(const short8*)(bp+k*32), acc,0,0,0);
    float bb = beo[col];
    #pragma unroll
    for (int r=0;r<4;r++){
      int row = mb + q*4 + r;
      float e0 = edges[(size_t)(p0+row)*128 + col];
      res[tt][r] = e0 + acc[r] + bb;
    }
  }
  #pragma unroll
  for (int r=0;r<4;r++){
    float s  = res[0][r]+res[1][r]+res[2][r]+res[3][r];
    float s2 = res[0][r]*res[0][r]+res[1][r]*res[1][r]+res[2][r]*res[2][r]+res[3][r]*res[3][r];
    s  += __shfl_xor(s,1);  s  += __shfl_xor(s,2);  s  += __shfl_xor(s,4);  s  += __shfl_xor(s,8);
    s2 += __shfl_xor(s2,1); s2 += __shfl_xor(s2,2); s2 += __shfl_xor(s2,4); s2 += __shfl_xor(s2,8);
    if (l15 == 0){
      int row = mb + q*4 + r;
      redS[row][cg] = s; redQ[row][cg] = s2;
    }
  }
  __syncthreads();
  if (t < 32){
    float s = redS[t][0] + redS[t][1];
    float s2 = redQ[t][0] + redQ[t][1];
    float m = s*(1.f/128);
    mrow[t] = m;
    irow[t] = rsqrtf(s2*(1.f/128) - m*m + 1e-5f);
  }
  __syncthreads();
  #pragma unroll
  for (int tt=0; tt<4; tt++){
    int col = cg*64 + tt*16 + l15;
    #pragma unroll
    for (int r=0;r<4;r++){
      int row = mb + q*4 + r;
      abuf[row*ASTR + col] = f2b(lrelu((res[tt][r] - mrow[row])*irow[row]));
    }
  }
  __syncthreads();

  // Phase 3: MLP GEMM1 (We1) -> h (bf16, reuse lbuf with ASTR stride)
  unsigned short* hbuf = lbuf;
  {
    short8 a2[4];
    #pragma unroll
    for (int k=0;k<4;k++) a2[k] = *(const short8*)(abuf + (mb+l15)*ASTR + k*32 + q*8);
    #pragma unroll
    for (int tt=0; tt<4; tt++){
      int col = cg*64 + tt*16 + l15;
      const unsigned short* bp = We1T + (size_t)col*128 + q*8;
      f32x4 acc = {0.f,0.f,0.f,0.f};
      #pragma unroll
      for (int k=0;k<4;k++)
        acc = __builtin_amdgcn_mfma_f32_16x16x32_bf16(a2[k], *(const short8*)(bp+k*32), acc,0,0,0);
      float bb = be1[col];
      #pragma unroll
      for (int r=0;r<4;r++){
        int row = mb + q*4 + r;
        hbuf[row*ASTR + col] = f2b(lrelu(acc[r] + bb));
      }
    }
  }
  __syncthreads();
  // Phase 4: MLP GEMM2 (We2) + residual, final store
  {
    short8 hf[4];
    #pragma unroll
    for (int k=0;k<4;k++) hf[k] = *(const short8*)(hbuf + (mb+l15)*ASTR + k*32 + q*8);
    #pragma unroll
    for (int tt=0; tt<4; tt++){
      int col = cg*64 + tt*16 + l15;
      const unsigned short* bp = We2T + (size_t)col*128 + q*8;
      f32x4 acc = {0.f,0.f,0.f,0.f};
      #pragma unroll
      for (int k=0;k<4;k++)
        acc = __builtin_amdgcn_mfma_f32_16x16x32_bf16(hf[k], *(const short8*)(bp+k*32), acc,0,0,0);
      float bb = be2[col];
      #pragma unroll
      for (int r=0;r<4;r++){
        int row = mb + q*4 + r;
        out_edges[(size_t)(p0+row)*128 + col] = res[tt][r] + acc[r] + bb;
      }
    }
  }
}

// ---- row softmax over transposed logits; scatter-write attn in [b,h,qi,ki] ----
__global__ void k_softmax(const float* __restrict__ logitsT, float* __restrict__ attn){
  int t = threadIdx.x, w = t>>6, l = t&63;
  int row = blockIdx.x*4 + w;          // (b*8+h)*128 + ki
  const float* src = logitsT + (size_t)row*128;
  float x0 = src[l], x1 = src[l+64];
  float mx = fmaxf(x0,x1);
  #pragma unroll
  for (int m=1;m<64;m<<=1) mx = fmaxf(mx, __shfl_xor(mx,m));
  float e0 = expf(x0-mx), e1 = expf(x1-mx);
  float s = e0+e1;
  #pragma unroll
  for (int m=1;m<64;m<<=1) s += __shfl_xor(s,m);
  float inv = 1.f/s;
  int bh = row>>7, ki = row&127;
  attn[((size_t)bh*128 + l)*128 + ki]    = e0*inv;
  attn[((size_t)bh*128 + l+64)*128 + ki] = e1*inv;
}

// ---- wv + dnodes fused, one block per (b,qi) ----
__global__ __launch_bounds__(256) void k_wv_dnodes(const float* __restrict__ attn,
    const float* __restrict__ qkv, const float* __restrict__ nodes,
    const float* __restrict__ Wno, const float* __restrict__ bno,
    float* __restrict__ nodes1){
  __shared__ float at[8][128];
  __shared__ float wvs[256];
  int row = blockIdx.x; int b = row>>7, qi = row&127;
  int t = threadIdx.x;
  #pragma unroll
  for (int i=0;i<4;i++){
    int idx = t + i*256; int h = idx>>7, ki = idx&127;
    at[h][ki] = attn[((size_t)(b*8+h)*128 + qi)*128 + ki];
  }
  __syncthreads();
  int h = t>>5;
  float acc = 0.f;
  for (int ki=0;ki<128;ki++)
    acc += at[h][ki] * qkv[(size_t)(b*128+ki)*768 + 512 + t];
  wvs[t] = acc;
  __syncthreads();
  float acc2 = bno[t];
  for (int kk=0;kk<256;kk++) acc2 += wvs[kk]*Wno[(size_t)kk*256 + t];
  nodes1[(size_t)row*256 + t] = nodes[(size_t)row*256 + t] + acc2;
}

// ---- film2 + mlp1 + mlp2 fused, one block per (b,n) row ----
__global__ __launch_bounds__(256) void k_nodeB(const float* __restrict__ nodes1,
    const float* __restrict__ cond, const float* __restrict__ Wn1, const float* __restrict__ bn1,
    const float* __restrict__ Wn2, const float* __restrict__ bn2, float* __restrict__ out){
  __shared__ float red[256];
  __shared__ float a[256];
  __shared__ float hid[1024];
  int row = blockIdx.x, t = threadIdx.x, b = row>>7;
  float v = nodes1[(size_t)row*256 + t];
  red[t] = v; __syncthreads();
  for (int s=128; s>0; s>>=1){ if (t<s) red[t]+=red[t+s]; __syncthreads(); }
  float m = red[0]*(1.f/256); __syncthreads();
  float d0 = v-m; red[t]=d0*d0; __syncthreads();
  for (int s=128; s>0; s>>=1){ if (t<s) red[t]+=red[t+s]; __syncthreads(); }
  float inv = rsqrtf(red[0]*(1.f/256)+1e-5f);
  a[t] = lrelu(d0*inv*(1.f+cond[b*1024+512+t]) + cond[b*1024+768+t]);
  __syncthreads();
  for (int i=0;i<4;i++){
    int j = t + i*256;
    float acc = bn1[j];
    for (int kk=0;kk<256;kk++) acc += a[kk]*Wn1[(size_t)kk*1024+j];
    hid[j] = lrelu(acc);
  }
  __syncthreads();
  float acc = bn2[t];
  for (int kk=0;kk<1024;kk++) acc += hid[kk]*Wn2[(size_t)kk*256+t];
  out[(size_t)row*256 + t] = v + acc;
}

extern "C" void kernel_launch(void* const* d_in, const int* in_sizes, int n_inp,
                              void* d_out, int out_size, void* d_ws, size_t ws_size,
                              hipStream_t stream){
  const float* nodes = (const float*)d_in[0];
  const float* edges = (const float*)d_in[1];
  const float* conds = (const float*)d_in[2];
  const float* Wc   = (const float*)d_in[3];
  const float* bc   = (const float*)d_in[4];
  const float* Wqkv = (const float*)d_in[5];
  const float* bqkv = (const float*)d_in[6];
  const float* Wss  = (const float*)d_in[7];
  const float* bss  = (const float*)d_in[8];
  const float* Wno  = (const float*)d_in[9];
  const float* bno  = (const float*)d_in[10];
  const float* Weo  = (const float*)d_in[11];
  const float* beo  = (const float*)d_in[12];
  const float* Wn1  = (const float*)d_in[13];
  const float* bn1  = (const float*)d_in[14];
  const float* Wn2  = (const float*)d_in[15];
  const float* bn2  = (const float*)d_in[16];
  const float* We1  = (const float*)d_in[17];
  const float* be1  = (const float*)d_in[18];
  const float* We2  = (const float*)d_in[19];
  const float* be2  = (const float*)d_in[20];

  float* ws      = (float*)d_ws;
  float* cond    = ws;                    // 4096
  float* qkvb    = cond + 4096;           // 393216
  float* logitsT = qkvb + 393216;         // 524288
  float* attn    = logitsT + 524288;      // 524288
  float* nodes1  = attn + 524288;         // 131072
  unsigned short* wbf = (unsigned short*)(nodes1 + 131072); // 131072 ushorts
  unsigned short* WssT = wbf;
  unsigned short* WeoT = wbf + 65536;
  unsigned short* We1T = wbf + 98304;
  unsigned short* We2T = wbf + 114688;

  float* out_nodes = (float*)d_out;
  float* out_edges = out_nodes + 131072;

  k_setup<<<516, 256, 0, stream>>>(Wss, Weo, We1, We2, conds, Wc, bc, wbf, cond);
  k_nodeA<<<BB*NN, 256, 0, stream>>>(nodes, cond, Wqkv, bqkv, qkvb);
  k_edge<<<BB*NN*NN/32, 256, 0, stream>>>(edges, qkvb, WssT, bss, WeoT, beo,
                                          We1T, be1, We2T, be2, logitsT, out_edges);
  k_softmax<<<BB*NH*NN/4, 256, 0, stream>>>(logitsT, attn);
  k_wv_dnodes<<<BB*NN, 256, 0, stream>>>(attn, qkvb, nodes, Wno, bno, nodes1);
  k_nodeB<<<BB*NN, 256, 0, stream>>>(nodes1, cond, Wn1, bn1, Wn2, bn2, out_nodes);
}

// Round 5
// 273.445 us; speedup vs baseline: 2.4034x; 1.4103x over previous
//
#include <hip/hip_runtime.h>
#include <hip/hip_bf16.h>

#define BB 4
#define NN 128
#define NH 8

typedef __attribute__((ext_vector_type(8))) short short8;
typedef __attribute__((ext_vector_type(4))) float f32x4;

__device__ __forceinline__ float lrelu(float x){ return fmaxf(x, 0.1f*x); }
__device__ __forceinline__ unsigned short f2b(float x){
  __hip_bfloat16 h = __float2bfloat16(x);
  return *reinterpret_cast<unsigned short*>(&h);
}
__device__ __forceinline__ short8 ldf(const unsigned short* p){ return *(const short8*)p; }

// ws ushort layout offsets (within wbf):
//  WssT 0 [512x128] | WeoT 65536 [128x256] | We1T 98304 [128x128] | We2T 114688 [128x128]
//  WqkvT 131072 [768x256] | WnoT 327680 [256x256] | Wn1T 393216 [1024x256] | Wn2T 655360 [256x1024]

// ---- setup: bf16 transposes (blocks 0..895) + cond GEMM (blocks 896..911) ----
__global__ void k_setup(const float* Wss, const float* Weo, const float* We1, const float* We2,
                        const float* Wqkv, const float* Wno, const float* Wn1, const float* Wn2,
                        const float* conds, const float* Wc, const float* bc,
                        unsigned short* wbf, float* cond){
  int bid = blockIdx.x, t = threadIdx.x;
  if (bid < 896){
    #pragma unroll
    for (int i = 0; i < 4; i++){
      int idx = bid*1024 + t + i*256;
      float v;
      if (idx < 65536){ int n = idx>>7, k = idx&127; v = Wss[(size_t)k*512+n]; }
      else if (idx < 98304){ int j = idx-65536; int n = j>>8, k = j&255; v = Weo[(size_t)k*128+n]; }
      else if (idx < 114688){ int j = idx-98304; int n = j>>7, k = j&127; v = We1[(size_t)k*128+n]; }
      else if (idx < 131072){ int j = idx-114688; int n = j>>7, k = j&127; v = We2[(size_t)k*128+n]; }
      else if (idx < 327680){ int j = idx-131072; int n = j>>8, k = j&255; v = Wqkv[(size_t)k*768+n]; }
      else if (idx < 393216){ int j = idx-327680; int n = j>>8, k = j&255; v = Wno[(size_t)k*256+n]; }
      else if (idx < 655360){ int j = idx-393216; int n = j>>8, k = j&255; v = Wn1[(size_t)k*1024+n]; }
      else { int j = idx-655360; int n = j>>10, k = j&1023; v = Wn2[(size_t)k*256+n]; }
      wbf[idx] = f2b(v);
    }
  } else {
    int i = bid - 896;
    int b = i >> 2, j = (i&3)*256 + t;
    __shared__ float c[256];
    c[t] = conds[(size_t)b*256 + t];
    __syncthreads();
    float acc = bc[j];
    for (int kk = 0; kk < 256; kk++) acc += c[kk]*Wc[(size_t)kk*1024 + j];
    cond[b*1024 + j] = acc;
  }
}

// ---- film1 + qkv (MFMA). 16 node-rows per block, grid 32. Emits q (fp32), kT (fp32), vT (bf16). ----
#define NSTR 260
__global__ __launch_bounds__(256) void k_nodeA(const float* __restrict__ nodes,
    const float* __restrict__ cond, const unsigned short* __restrict__ WqkvT,
    const float* __restrict__ bqkv, float* __restrict__ qbuf,
    float* __restrict__ kT, unsigned short* __restrict__ vT){
  __shared__ float nbuf[16*NSTR];
  __shared__ __align__(16) unsigned short abuf[16*264];
  __shared__ float psum[256], psq[256], mrow[16], irow[16];
  int t = threadIdx.x;
  int b = blockIdx.x >> 3, n0 = (blockIdx.x & 7)*16;
  int l = t & 63, w = t >> 6, l15 = l & 15, q = l >> 4;

  const float4* src = (const float4*)(nodes + ((size_t)(b*128+n0))*256);
  #pragma unroll
  for (int i = 0; i < 4; i++){
    int f = t + i*256; int r = f >> 6, c4 = f & 63;
    *(float4*)(nbuf + r*NSTR + c4*4) = src[f];
  }
  __syncthreads();
  {
    int r = t >> 4, p = t & 15;
    float s = 0.f, s2 = 0.f;
    #pragma unroll
    for (int i = 0; i < 16; i++){ float v = nbuf[r*NSTR + p + 16*i]; s += v; s2 += v*v; }
    psum[t] = s; psq[t] = s2;
  }
  __syncthreads();
  if (t < 16){
    float s = 0.f, s2 = 0.f;
    #pragma unroll
    for (int i = 0; i < 16; i++){ s += psum[t*16+i]; s2 += psq[t*16+i]; }
    float m = s*(1.f/256);
    mrow[t] = m; irow[t] = rsqrtf(s2*(1.f/256) - m*m + 1e-5f);
  }
  __syncthreads();
  #pragma unroll
  for (int i = 0; i < 16; i++){
    int f = t + i*256; int r = f >> 8, c = f & 255;
    float x = (nbuf[r*NSTR+c]-mrow[r])*irow[r]*(1.f+cond[b*1024+c]) + cond[b*1024+256+c];
    abuf[r*264+c] = f2b(lrelu(x));
  }
  __syncthreads();
  short8 af[8];
  #pragma unroll
  for (int k = 0; k < 8; k++) af[k] = ldf(abuf + l15*264 + k*32 + q*8);
  #pragma unroll
  for (int tt = 0; tt < 12; tt++){
    int c = w*192 + tt*16 + l15;
    const unsigned short* bp = WqkvT + (size_t)c*256 + q*8;
    f32x4 acc = {0.f,0.f,0.f,0.f};
    #pragma unroll
    for (int k = 0; k < 8; k++) acc = __builtin_amdgcn_mfma_f32_16x16x32_bf16(af[k], ldf(bp + k*32), acc,0,0,0);
    float bb = bqkv[c];
    if (c < 256){
      #pragma unroll
      for (int r = 0; r < 4; r++) qbuf[(size_t)(b*128+n0+q*4+r)*256 + c] = acc[r] + bb;
    } else if (c < 512){
      float4 kv; kv.x = acc[0]+bb; kv.y = acc[1]+bb; kv.z = acc[2]+bb; kv.w = acc[3]+bb;
      *(float4*)(kT + ((size_t)(b*256 + c-256))*128 + n0 + q*4) = kv;
    } else {
      ushort4 vv; vv.x = f2b(acc[0]+bb); vv.y = f2b(acc[1]+bb); vv.z = f2b(acc[2]+bb); vv.w = f2b(acc[3]+bb);
      *(ushort4*)(vT + ((size_t)(b*256 + c-512))*128 + n0 + q*4) = vv;
    }
  }
}

// ---- fused edge path (restructured for ILP): 32 rows/block, grid 2048 ----
#define ASTR 136
#define LSTR 264
__global__ __launch_bounds__(256,4) void k_edge(
    const float* __restrict__ edges, const float* __restrict__ qbuf, const float* __restrict__ kT,
    const unsigned short* __restrict__ WssT, const float* __restrict__ bss,
    const unsigned short* __restrict__ WeoT, const float* __restrict__ beo,
    const unsigned short* __restrict__ We1T, const float* __restrict__ be1,
    const unsigned short* __restrict__ We2T, const float* __restrict__ be2,
    float* __restrict__ logitsT, float* __restrict__ out_edges){
  __shared__ __align__(16) unsigned short abuf[32*ASTR];
  __shared__ __align__(16) unsigned short lbuf[32*LSTR];
  __shared__ float qvs[256], lgs[256];
  __shared__ float redS[32][4], redQ[32][4], mrow[32], irow[32];

  int t = threadIdx.x;
  int p0 = blockIdx.x * 32;
  int b  = p0 >> 14, qi = (p0 >> 7) & 127, ki0 = p0 & 127;
  int l = t & 63, w = t >> 6, l15 = l & 15, q = l >> 4;

  // P0: stage edges + LN(lrelu) -> abuf
  {
    qvs[t] = qbuf[(size_t)(b*128 + qi)*256 + t];
    const float4* src = (const float4*)(edges + (size_t)p0*128);
    int c4 = t & 31, rbase = t >> 5;
    float4 ev[4];
    #pragma unroll
    for (int i=0;i<4;i++) ev[i] = src[t + i*256];
    #pragma unroll
    for (int i=0;i<4;i++){
      int r = rbase + i*8;
      float s  = ev[i].x + ev[i].y + ev[i].z + ev[i].w;
      float s2 = ev[i].x*ev[i].x + ev[i].y*ev[i].y + ev[i].z*ev[i].z + ev[i].w*ev[i].w;
      #pragma unroll
      for (int mm=1; mm<32; mm<<=1){ s += __shfl_xor(s,mm); s2 += __shfl_xor(s2,mm); }
      float m = s*(1.f/128);
      float inv = rsqrtf(s2*(1.f/128) - m*m + 1e-5f);
      ushort4 pk;
      pk.x = f2b(lrelu((ev[i].x - m)*inv)); pk.y = f2b(lrelu((ev[i].y - m)*inv));
      pk.z = f2b(lrelu((ev[i].z - m)*inv)); pk.w = f2b(lrelu((ev[i].w - m)*inv));
      *(ushort4*)(abuf + r*ASTR + c4*4) = pk;
    }
  }
  __syncthreads();

  // P1: ss GEMM, wave = 32 rows x 64 cols (B frags reused across 2 row-strips)
  const float isd = 0.17677669529663687f;
  {
    short8 af[2][4];
    #pragma unroll
    for (int s=0;s<2;s++)
      #pragma unroll
      for (int k=0;k<4;k++) af[s][k] = ldf(abuf + (s*16+l15)*ASTR + k*32 + q*8);
    float hsPrev[2][4];
    #pragma unroll
    for (int tt=0; tt<4; tt++){
      int c = w*64 + tt*16 + l15;
      const unsigned short* bsp = WssT + (size_t)c*128 + q*8;
      const unsigned short* bcp = WssT + (size_t)(c+256)*128 + q*8;
      f32x4 aS[2], aC[2];
      aS[0]={0.f,0.f,0.f,0.f}; aS[1]=aS[0]; aC[0]=aS[0]; aC[1]=aS[0];
      #pragma unroll
      for (int k=0;k<4;k++){
        short8 b0 = ldf(bsp + k*32);
        short8 b1 = ldf(bcp + k*32);
        aS[0] = __builtin_amdgcn_mfma_f32_16x16x32_bf16(af[0][k], b0, aS[0],0,0,0);
        aS[1] = __builtin_amdgcn_mfma_f32_16x16x32_bf16(af[1][k], b0, aS[1],0,0,0);
        aC[0] = __builtin_amdgcn_mfma_f32_16x16x32_bf16(af[0][k], b1, aC[0],0,0,0);
        aC[1] = __builtin_amdgcn_mfma_f32_16x16x32_bf16(af[1][k], b1, aC[1],0,0,0);
      }
      float bS = bss[c], bC = bss[256+c], qv = qvs[c];
      float hs[2][4];
      #pragma unroll
      for (int s=0;s<2;s++){
        float4 kv4 = *(const float4*)(kT + ((size_t)(b*256+c))*128 + ki0 + s*16 + q*4);
        float kvv[4] = {kv4.x, kv4.y, kv4.z, kv4.w};
        #pragma unroll
        for (int r=0;r<4;r++){
          int row = s*16 + q*4 + r;
          float ne = qv*kvv[r]*(1.f + aC[s][r] + bC) + aS[s][r] + bS;
          lbuf[row*LSTR + c] = f2b(lrelu(ne));
          float vv = ne;
          vv += __shfl_xor(vv,1); vv += __shfl_xor(vv,2);
          vv += __shfl_xor(vv,4); vv += __shfl_xor(vv,8);
          hs[s][r] = vv;
        }
      }
      if (tt & 1){
        if (l15 == 0){
          int h = w*2 + (tt>>1);
          #pragma unroll
          for (int s=0;s<2;s++)
            #pragma unroll
            for (int r=0;r<4;r++)
              lgs[h*32 + s*16 + q*4 + r] = hsPrev[s][r] + hs[s][r];
        }
      } else {
        #pragma unroll
        for (int s=0;s<2;s++)
          #pragma unroll
          for (int r=0;r<4;r++) hsPrev[s][r] = hs[s][r];
      }
    }
  }
  __syncthreads();
  logitsT[((size_t)(b*8 + (t>>5))*128 + ki0 + (t&31))*128 + qi] = lgs[t] * isd;

  // P2: Weo GEMM (K=256) + residual; wave = 32 rows x 32 cols
  float res[2][2][4];
  {
    f32x4 acc[2][2];
    acc[0][0]={0.f,0.f,0.f,0.f}; acc[0][1]=acc[0][0]; acc[1][0]=acc[0][0]; acc[1][1]=acc[0][0];
    #pragma unroll
    for (int k=0;k<8;k++){
      short8 lf0 = ldf(lbuf + l15*LSTR + k*32 + q*8);
      short8 lf1 = ldf(lbuf + (16+l15)*LSTR + k*32 + q*8);
      #pragma unroll
      for (int tt=0;tt<2;tt++){
        int c = w*32 + tt*16 + l15;
        short8 bf = ldf(WeoT + (size_t)c*256 + k*32 + q*8);
        acc[tt][0] = __builtin_amdgcn_mfma_f32_16x16x32_bf16(lf0, bf, acc[tt][0],0,0,0);
        acc[tt][1] = __builtin_amdgcn_mfma_f32_16x16x32_bf16(lf1, bf, acc[tt][1],0,0,0);
      }
    }
    #pragma unroll
    for (int tt=0;tt<2;tt++){
      int c = w*32 + tt*16 + l15;
      float bb = beo[c];
      #pragma unroll
      for (int s=0;s<2;s++)
        #pragma unroll
        for (int r=0;r<4;r++){
          int row = s*16 + q*4 + r;
          res[tt][s][r] = edges[(size_t)(p0+row)*128 + c] + acc[tt][s][r] + bb;
        }
    }
  }
  // LN2 stats
  #pragma unroll
  for (int s=0;s<2;s++)
    #pragma unroll
    for (int r=0;r<4;r++){
      float ps = res[0][s][r] + res[1][s][r];
      float p2 = res[0][s][r]*res[0][s][r] + res[1][s][r]*res[1][s][r];
      ps += __shfl_xor(ps,1); ps += __shfl_xor(ps,2); ps += __shfl_xor(ps,4); ps += __shfl_xor(ps,8);
      p2 += __shfl_xor(p2,1); p2 += __shfl_xor(p2,2); p2 += __shfl_xor(p2,4); p2 += __shfl_xor(p2,8);
      if (l15 == 0){ redS[s*16+q*4+r][w] = ps; redQ[s*16+q*4+r][w] = p2; }
    }
  __syncthreads();
  if (t < 32){
    float s = redS[t][0]+redS[t][1]+redS[t][2]+redS[t][3];
    float s2 = redQ[t][0]+redQ[t][1]+redQ[t][2]+redQ[t][3];
    float m = s*(1.f/128);
    mrow[t] = m; irow[t] = rsqrtf(s2*(1.f/128) - m*m + 1e-5f);
  }
  __syncthreads();
  #pragma unroll
  for (int tt=0;tt<2;tt++){
    int c = w*32 + tt*16 + l15;
    #pragma unroll
    for (int s=0;s<2;s++)
      #pragma unroll
      for (int r=0;r<4;r++){
        int row = s*16 + q*4 + r;
        abuf[row*ASTR + c] = f2b(lrelu((res[tt][s][r] - mrow[row])*irow[row]));
      }
  }
  __syncthreads();

  // P3: We1 GEMM (K=128) -> hbuf (reuse lbuf)
  unsigned short* hbuf = lbuf;
  {
    short8 af2[2][4];
    #pragma unroll
    for (int s=0;s<2;s++)
      #pragma unroll
      for (int k=0;k<4;k++) af2[s][k] = ldf(abuf + (s*16+l15)*ASTR + k*32 + q*8);
    #pragma unroll
    for (int tt=0;tt<2;tt++){
      int c = w*32 + tt*16 + l15;
      const unsigned short* bp = We1T + (size_t)c*128 + q*8;
      f32x4 acc[2];
      acc[0]={0.f,0.f,0.f,0.f}; acc[1]=acc[0];
      #pragma unroll
      for (int k=0;k<4;k++){
        short8 bf = ldf(bp + k*32);
        acc[0] = __builtin_amdgcn_mfma_f32_16x16x32_bf16(af2[0][k], bf, acc[0],0,0,0);
        acc[1] = __builtin_amdgcn_mfma_f32_16x16x32_bf16(af2[1][k], bf, acc[1],0,0,0);
      }
      float bb = be1[c];
      #pragma unroll
      for (int s=0;s<2;s++)
        #pragma unroll
        for (int r=0;r<4;r++)
          hbuf[(s*16+q*4+r)*ASTR + c] = f2b(lrelu(acc[s][r] + bb));
    }
  }
  __syncthreads();
  // P4: We2 GEMM (K=128) + residual -> out
  {
    f32x4 acc[2][2];
    acc[0][0]={0.f,0.f,0.f,0.f}; acc[0][1]=acc[0][0]; acc[1][0]=acc[0][0]; acc[1][1]=acc[0][0];
    #pragma unroll
    for (int k=0;k<4;k++){
      short8 hf0 = ldf(hbuf + l15*ASTR + k*32 + q*8);
      short8 hf1 = ldf(hbuf + (16+l15)*ASTR + k*32 + q*8);
      #pragma unroll
      for (int tt=0;tt<2;tt++){
        int c = w*32 + tt*16 + l15;
        short8 bf = ldf(We2T + (size_t)c*128 + k*32 + q*8);
        acc[tt][0] = __builtin_amdgcn_mfma_f32_16x16x32_bf16(hf0, bf, acc[tt][0],0,0,0);
        acc[tt][1] = __builtin_amdgcn_mfma_f32_16x16x32_bf16(hf1, bf, acc[tt][1],0,0,0);
      }
    }
    #pragma unroll
    for (int tt=0;tt<2;tt++){
      int c = w*32 + tt*16 + l15;
      float bb = be2[c];
      #pragma unroll
      for (int s=0;s<2;s++)
        #pragma unroll
        for (int r=0;r<4;r++){
          int row = s*16 + q*4 + r;
          out_edges[(size_t)(p0+row)*128 + c] = res[tt][s][r] + acc[tt][s][r] + bb;
        }
    }
  }
}

// ---- softmax over q axis; bf16 output in [b,h,qi,ki] ----
__global__ void k_softmax(const float* __restrict__ logitsT, unsigned short* __restrict__ attnB){
  int t = threadIdx.x, w = t>>6, l = t&63;
  int row = blockIdx.x*4 + w;          // (b*8+h)*128 + ki
  const float* src = logitsT + (size_t)row*128;
  float x0 = src[l], x1 = src[l+64];
  float mx = fmaxf(x0,x1);
  #pragma unroll
  for (int m=1;m<64;m<<=1) mx = fmaxf(mx, __shfl_xor(mx,m));
  float e0 = expf(x0-mx), e1 = expf(x1-mx);
  float s = e0+e1;
  #pragma unroll
  for (int m=1;m<64;m<<=1) s += __shfl_xor(s,m);
  float inv = 1.f/s;
  int bh = row>>7, ki = row&127;
  attnB[((size_t)bh*128 + l)*128 + ki]    = f2b(e0*inv);
  attnB[((size_t)bh*128 + l+64)*128 + ki] = f2b(e1*inv);
}

// ---- mega node kernel: wv -> Wno+residual -> film2 -> mlp1 -> mlp2+residual ----
#define HSTR 1040
__global__ __launch_bounds__(256,2) void k_node(
    const unsigned short* __restrict__ attnB, const unsigned short* __restrict__ vT,
    const float* __restrict__ nodes, const float* __restrict__ cond,
    const unsigned short* __restrict__ WnoT, const float* __restrict__ bno,
    const unsigned short* __restrict__ Wn1T, const float* __restrict__ bn1,
    const unsigned short* __restrict__ Wn2T, const float* __restrict__ bn2,
    float* __restrict__ out_nodes){
  __shared__ __align__(16) unsigned short abuf[16*264];
  __shared__ __align__(16) unsigned short hbuf[16*HSTR];
  __shared__ float redS[16][4], redQ[16][4], mrow[16], irow[16];
  int t = threadIdx.x;
  int b = blockIdx.x >> 3, n0 = (blockIdx.x & 7)*16;
  int l = t & 63, w = t >> 6, l15 = l & 15, q = l >> 4;

  // P0: wv GEMM (K=128): A=attn rows, B=vT; wave covers cols [w*64, w*64+64)
  f32x4 wacc[4];
  #pragma unroll
  for (int hh=0; hh<2; hh++){
    int h = w*2 + hh;
    const unsigned short* ap = attnB + ((size_t)(b*8+h)*128 + n0 + l15)*128 + q*8;
    short8 af[4];
    #pragma unroll
    for (int k=0;k<4;k++) af[k] = ldf(ap + k*32);
    #pragma unroll
    for (int t2=0;t2<2;t2++){
      int tt = hh*2 + t2;
      int c = w*64 + tt*16 + l15;
      const unsigned short* bp = vT + (size_t)(b*256+c)*128 + q*8;
      f32x4 acc = {0.f,0.f,0.f,0.f};
      #pragma unroll
      for (int k=0;k<4;k++) acc = __builtin_amdgcn_mfma_f32_16x16x32_bf16(af[k], ldf(bp + k*32), acc,0,0,0);
      wacc[tt] = acc;
    }
  }
  #pragma unroll
  for (int tt=0;tt<4;tt++)
    #pragma unroll
    for (int r=0;r<4;r++)
      abuf[(q*4+r)*264 + (w*64+tt*16+l15)] = f2b(wacc[tt][r]);
  __syncthreads();

  // P2: Wno GEMM (K=256) + residual (nodes)
  float res[4][4];
  {
    short8 af[8];
    #pragma unroll
    for (int k=0;k<8;k++) af[k] = ldf(abuf + l15*264 + k*32 + q*8);
    #pragma unroll
    for (int tt=0;tt<4;tt++){
      int c = w*64 + tt*16 + l15;
      const unsigned short* bp = WnoT + (size_t)c*256 + q*8;
      f32x4 acc = {0.f,0.f,0.f,0.f};
      #pragma unroll
      for (int k=0;k<8;k++) acc = __builtin_amdgcn_mfma_f32_16x16x32_bf16(af[k], ldf(bp + k*32), acc,0,0,0);
      float bb = bno[c];
      #pragma unroll
      for (int r=0;r<4;r++)
        res[tt][r] = nodes[(size_t)(b*128+n0+q*4+r)*256 + c] + acc[r] + bb;
    }
  }
  // P3: LN stats over 256 cols
  #pragma unroll
  for (int r=0;r<4;r++){
    float ps = res[0][r]+res[1][r]+res[2][r]+res[3][r];
    float p2 = res[0][r]*res[0][r]+res[1][r]*res[1][r]+res[2][r]*res[2][r]+res[3][r]*res[3][r];
    ps += __shfl_xor(ps,1); ps += __shfl_xor(ps,2); ps += __shfl_xor(ps,4); ps += __shfl_xor(ps,8);
    p2 += __shfl_xor(p2,1); p2 += __shfl_xor(p2,2); p2 += __shfl_xor(p2,4); p2 += __shfl_xor(p2,8);
    if (l15 == 0){ redS[q*4+r][w] = ps; redQ[q*4+r][w] = p2; }
  }
  __syncthreads();
  if (t < 16){
    float s = redS[t][0]+redS[t][1]+redS[t][2]+redS[t][3];
    float s2 = redQ[t][0]+redQ[t][1]+redQ[t][2]+redQ[t][3];
    float m = s*(1.f/256);
    mrow[t] = m; irow[t] = rsqrtf(s2*(1.f/256) - m*m + 1e-5f);
  }
  __syncthreads();
  // P4: film2 -> abuf
  #pragma unroll
  for (int tt=0;tt<4;tt++){
    int c = w*64 + tt*16 + l15;
    float mul = 1.f + cond[b*1024 + 512 + c];
    float add = cond[b*1024 + 768 + c];
    #pragma unroll
    for (int r=0;r<4;r++){
      int row = q*4+r;
      float x = (res[tt][r] - mrow[row])*irow[row]*mul + add;
      abuf[row*264 + c] = f2b(lrelu(x));
    }
  }
  __syncthreads();
  // P5: mlp1 (K=256 -> 1024 cols); wave covers [w*256, w*256+256)
  {
    short8 af[8];
    #pragma unroll
    for (int k=0;k<8;k++) af[k] = ldf(abuf + l15*264 + k*32 + q*8);
    #pragma unroll
    for (int tt=0;tt<16;tt++){
      int c = w*256 + tt*16 + l15;
      const unsigned short* bp = Wn1T + (size_t)c*256 + q*8;
      f32x4 acc = {0.f,0.f,0.f,0.f};
      #pragma unroll
      for (int k=0;k<8;k++) acc = __builtin_amdgcn_mfma_f32_16x16x32_bf16(af[k], ldf(bp + k*32), acc,0,0,0);
      float bb = bn1[c];
      #pragma unroll
      for (int r=0;r<4;r++)
        hbuf[(q*4+r)*HSTR + c] = f2b(lrelu(acc[r] + bb));
    }
  }
  __syncthreads();
  // P6: mlp2 (K=1024 -> 256 cols) + residual
  {
    f32x4 acc2[4];
    acc2[0]={0.f,0.f,0.f,0.f}; acc2[1]=acc2[0]; acc2[2]=acc2[0]; acc2[3]=acc2[0];
    for (int k=0;k<32;k++){
      short8 hf = ldf(hbuf + l15*HSTR + k*32 + q*8);
      #pragma unroll
      for (int tt=0;tt<4;tt++){
        int c = w*64 + tt*16 + l15;
        short8 bf = ldf(Wn2T + (size_t)c*1024 + k*32 + q*8);
        acc2[tt] = __builtin_amdgcn_mfma_f32_16x16x32_bf16(hf, bf, acc2[tt],0,0,0);
      }
    }
    #pragma unroll
    for (int tt=0;tt<4;tt++){
      int c = w*64 + tt*16 + l15;
      float bb = bn2[c];
      #pragma unroll
      for (int r=0;r<4;r++)
        out_nodes[(size_t)(b*128+n0+q*4+r)*256 + c] = res[tt][r] + acc2[tt][r] + bb;
    }
  }
}

extern "C" void kernel_launch(void* const* d_in, const int* in_sizes, int n_inp,
                              void* d_out, int out_size, void* d_ws, size_t ws_size,
                              hipStream_t stream){
  const float* nodes = (const float*)d_in[0];
  const float* edges = (const float*)d_in[1];
  const float* conds = (const float*)d_in[2];
  const float* Wc   = (const float*)d_in[3];
  const float* bc   = (const float*)d_in[4];
  const float* Wqkv = (const float*)d_in[5];
  const float* bqkv = (const float*)d_in[6];
  const float* Wss  = (const float*)d_in[7];
  const float* bss  = (const float*)d_in[8];
  const float* Wno  = (const float*)d_in[9];
  const float* bno  = (const float*)d_in[10];
  const float* Weo  = (const float*)d_in[11];
  const float* beo  = (const float*)d_in[12];
  const float* Wn1  = (const float*)d_in[13];
  const float* bn1  = (const float*)d_in[14];
  const float* Wn2  = (const float*)d_in[15];
  const float* bn2  = (const float*)d_in[16];
  const float* We1  = (const float*)d_in[17];
  const float* be1  = (const float*)d_in[18];
  const float* We2  = (const float*)d_in[19];
  const float* be2  = (const float*)d_in[20];

  float* ws      = (float*)d_ws;
  float* cond    = ws;                       // 4096
  float* qbuf    = cond + 4096;              // 131072
  float* kT      = qbuf + 131072;            // 131072
  float* logitsT = kT + 131072;              // 524288
  unsigned short* attnB = (unsigned short*)(logitsT + 524288);  // 524288 ushorts
  unsigned short* vT    = attnB + 524288;                        // 131072 ushorts
  unsigned short* wbf   = vT + 131072;                           // 917504 ushorts

  unsigned short* WssT  = wbf;
  unsigned short* WeoT  = wbf + 65536;
  unsigned short* We1T  = wbf + 98304;
  unsigned short* We2T  = wbf + 114688;
  unsigned short* WqkvT = wbf + 131072;
  unsigned short* WnoT  = wbf + 327680;
  unsigned short* Wn1T  = wbf + 393216;
  unsigned short* Wn2T  = wbf + 655360;

  float* out_nodes = (float*)d_out;
  float* out_edges = out_nodes + 131072;

  k_setup<<<912, 256, 0, stream>>>(Wss, Weo, We1, We2, Wqkv, Wno, Wn1, Wn2,
                                   conds, Wc, bc, wbf, cond);
  k_nodeA<<<32, 256, 0, stream>>>(nodes, cond, WqkvT, bqkv, qbuf, kT, vT);
  k_edge<<<BB*NN*NN/32, 256, 0, stream>>>(edges, qbuf, kT, WssT, bss, WeoT, beo,
                                          We1T, be1, We2T, be2, logitsT, out_edges);
  k_softmax<<<BB*NH*NN/4, 256, 0, stream>>>(logitsT, attnB);
  k_node<<<32, 256, 0, stream>>>(attnB, vT, nodes, cond, WnoT, bno, Wn1T, bn1,
                                 Wn2T, bn2, out_nodes);
}

// Round 6
// 260.636 us; speedup vs baseline: 2.5215x; 1.0491x over previous
//
#include <hip/hip_runtime.h>
#include <hip/hip_bf16.h>

#define BB 4
#define NN 128
#define NH 8

typedef __attribute__((ext_vector_type(8))) short short8;
typedef __attribute__((ext_vector_type(4))) float f32x4;

__device__ __forceinline__ float lrelu(float x){ return fmaxf(x, 0.1f*x); }
__device__ __forceinline__ unsigned short f2b(float x){
  __hip_bfloat16 h = __float2bfloat16(x);
  return *reinterpret_cast<unsigned short*>(&h);
}
__device__ __forceinline__ short8 ldf(const unsigned short* p){ return *(const short8*)p; }

// wbf ushort offsets: WssT 0 [512x128] | WeoT 65536 [128x256] | We1T 98304 [128x128]
// We2T 114688 [128x128] | WqkvT 131072 [768x256] | WnoT 327680 [256x256]
// Wn1T 393216 [1024x256] | Wn2T 655360 [256x1024]

// ---- setup: LDS-tiled bf16 transposes (tiles 0..895) + cond GEMM (896..911) ----
__global__ __launch_bounds__(256) void k_setup(
    const float* Wss, const float* Weo, const float* We1, const float* We2,
    const float* Wqkv, const float* Wno, const float* Wn1, const float* Wn2,
    const float* conds, const float* Wc, const float* bc,
    unsigned short* wbf, float* cond){
  __shared__ float tile[32][33];
  __shared__ float c[256];
  int bid = blockIdx.x, t = threadIdx.x;
  if (bid < 896){
    const float* src; int K, N; size_t doff; int tid;
    if      (bid < 64)  { src=Wss;  K=128;  N=512;  doff=0;      tid=bid; }
    else if (bid < 96)  { src=Weo;  K=256;  N=128;  doff=65536;  tid=bid-64; }
    else if (bid < 112) { src=We1;  K=128;  N=128;  doff=98304;  tid=bid-96; }
    else if (bid < 128) { src=We2;  K=128;  N=128;  doff=114688; tid=bid-112; }
    else if (bid < 320) { src=Wqkv; K=256;  N=768;  doff=131072; tid=bid-128; }
    else if (bid < 384) { src=Wno;  K=256;  N=256;  doff=327680; tid=bid-320; }
    else if (bid < 640) { src=Wn1;  K=256;  N=1024; doff=393216; tid=bid-384; }
    else                { src=Wn2;  K=1024; N=256;  doff=655360; tid=bid-640; }
    int ntk = K >> 5;
    int k0 = (tid % ntk) * 32, n0 = (tid / ntk) * 32;
    int r = t >> 3, c4 = (t & 7) * 4;
    float4 v = *(const float4*)(src + (size_t)(k0+r)*N + n0 + c4);
    tile[r][c4+0]=v.x; tile[r][c4+1]=v.y; tile[r][c4+2]=v.z; tile[r][c4+3]=v.w;
    __syncthreads();
    ushort4 o;
    o.x = f2b(tile[c4+0][r]); o.y = f2b(tile[c4+1][r]);
    o.z = f2b(tile[c4+2][r]); o.w = f2b(tile[c4+3][r]);
    *(ushort4*)(wbf + doff + (size_t)(n0+r)*K + k0 + c4) = o;
  } else {
    int i = bid - 896;
    int b = i >> 2, j = (i&3)*256 + t;
    c[t] = conds[(size_t)b*256 + t];
    __syncthreads();
    float acc = bc[j];
    for (int kk = 0; kk < 256; kk++) acc += c[kk]*Wc[(size_t)kk*1024 + j];
    cond[b*1024 + j] = acc;
  }
}

// ---- film1 + qkv (MFMA). 16 rows x 192-col slice per block, grid 128 ----
#define NSTR 260
__global__ __launch_bounds__(256) void k_nodeA(const float* __restrict__ nodes,
    const float* __restrict__ cond, const unsigned short* __restrict__ WqkvT,
    const float* __restrict__ bqkv, float* __restrict__ qbuf,
    float* __restrict__ kT, unsigned short* __restrict__ vT){
  __shared__ float nbuf[16*NSTR];
  __shared__ __align__(16) unsigned short abuf[16*264];
  __shared__ float psum[256], psq[256], mrow[16], irow[16];
  int t = threadIdx.x;
  int rg = blockIdx.x >> 2, slice = blockIdx.x & 3;
  int b = rg >> 3, n0 = (rg & 7)*16;
  int l = t & 63, w = t >> 6, l15 = l & 15, q = l >> 4;

  const float4* src = (const float4*)(nodes + ((size_t)(b*128+n0))*256);
  #pragma unroll
  for (int i = 0; i < 4; i++){
    int f = t + i*256; int r = f >> 6, c4 = f & 63;
    *(float4*)(nbuf + r*NSTR + c4*4) = src[f];
  }
  __syncthreads();
  {
    int r = t >> 4, p = t & 15;
    float s = 0.f, s2 = 0.f;
    #pragma unroll
    for (int i = 0; i < 16; i++){ float v = nbuf[r*NSTR + p + 16*i]; s += v; s2 += v*v; }
    psum[t] = s; psq[t] = s2;
  }
  __syncthreads();
  if (t < 16){
    float s = 0.f, s2 = 0.f;
    #pragma unroll
    for (int i = 0; i < 16; i++){ s += psum[t*16+i]; s2 += psq[t*16+i]; }
    float m = s*(1.f/256);
    mrow[t] = m; irow[t] = rsqrtf(s2*(1.f/256) - m*m + 1e-5f);
  }
  __syncthreads();
  #pragma unroll
  for (int i = 0; i < 16; i++){
    int f = t + i*256; int r = f >> 8, cc = f & 255;
    float x = (nbuf[r*NSTR+cc]-mrow[r])*irow[r]*(1.f+cond[b*1024+cc]) + cond[b*1024+256+cc];
    abuf[r*264+cc] = f2b(lrelu(x));
  }
  __syncthreads();
  short8 af[8];
  #pragma unroll
  for (int k = 0; k < 8; k++) af[k] = ldf(abuf + l15*264 + k*32 + q*8);
  #pragma unroll
  for (int tt = 0; tt < 3; tt++){
    int cc = slice*192 + w*48 + tt*16 + l15;
    const unsigned short* bp = WqkvT + (size_t)cc*256 + q*8;
    f32x4 acc = {0.f,0.f,0.f,0.f};
    #pragma unroll
    for (int k = 0; k < 8; k++) acc = __builtin_amdgcn_mfma_f32_16x16x32_bf16(af[k], ldf(bp + k*32), acc,0,0,0);
    float bb = bqkv[cc];
    if (cc < 256){
      #pragma unroll
      for (int r = 0; r < 4; r++) qbuf[(size_t)(b*128+n0+q*4+r)*256 + cc] = acc[r] + bb;
    } else if (cc < 512){
      float4 kv; kv.x = acc[0]+bb; kv.y = acc[1]+bb; kv.z = acc[2]+bb; kv.w = acc[3]+bb;
      *(float4*)(kT + ((size_t)(b*256 + cc-256))*128 + n0 + q*4) = kv;
    } else {
      ushort4 vv; vv.x = f2b(acc[0]+bb); vv.y = f2b(acc[1]+bb); vv.z = f2b(acc[2]+bb); vv.w = f2b(acc[3]+bb);
      *(ushort4*)(vT + ((size_t)(b*256 + cc-512))*128 + n0 + q*4) = vv;
    }
  }
}

// ---- fused edge path, 512 threads (8 waves), 32 rows/block, grid 2048 ----
#define ASTR 136
#define LSTR 264
__global__ __launch_bounds__(512) void k_edge(
    const float* __restrict__ edges, const float* __restrict__ qbuf, const float* __restrict__ kT,
    const unsigned short* __restrict__ WssT, const float* __restrict__ bss,
    const unsigned short* __restrict__ WeoT, const float* __restrict__ beo,
    const unsigned short* __restrict__ We1T, const float* __restrict__ be1,
    const unsigned short* __restrict__ We2T, const float* __restrict__ be2,
    float* __restrict__ logitsT, float* __restrict__ out_edges){
  __shared__ __align__(16) unsigned short abuf[32*ASTR];
  __shared__ __align__(16) unsigned short lbuf[32*LSTR];
  __shared__ float qvs[256], lgs[256];
  __shared__ float redS[32][8], redQ[32][8], mrow[32], irow[32];

  int t = threadIdx.x;
  int p0 = blockIdx.x * 32;
  int b  = p0 >> 14, qi = (p0 >> 7) & 127, ki0 = p0 & 127;
  int w = t >> 6, l15 = t & 15, q = (t & 63) >> 4;

  // P0: stage edges + per-row LN (32-lane shuffle) -> abuf
  {
    if (t < 256) qvs[t] = qbuf[(size_t)(b*128 + qi)*256 + t];
    const float4* src = (const float4*)(edges + (size_t)p0*128);
    #pragma unroll
    for (int i=0;i<2;i++){
      int idx = t + i*512;
      float4 ev = src[idx];
      int r = idx >> 5, c4 = idx & 31;
      float s  = ev.x + ev.y + ev.z + ev.w;
      float s2 = ev.x*ev.x + ev.y*ev.y + ev.z*ev.z + ev.w*ev.w;
      #pragma unroll
      for (int mm=1; mm<32; mm<<=1){ s += __shfl_xor(s,mm); s2 += __shfl_xor(s2,mm); }
      float m = s*(1.f/128);
      float inv = rsqrtf(s2*(1.f/128) - m*m + 1e-5f);
      ushort4 pk;
      pk.x = f2b(lrelu((ev.x - m)*inv)); pk.y = f2b(lrelu((ev.y - m)*inv));
      pk.z = f2b(lrelu((ev.z - m)*inv)); pk.w = f2b(lrelu((ev.w - m)*inv));
      *(ushort4*)(abuf + r*ASTR + c4*4) = pk;
    }
  }
  __syncthreads();

  // P1: ss GEMM; wave w owns ne-cols [w*32, w*32+32) (head h=w), both 16-row strips
  const float isd = 0.17677669529663687f;
  {
    short8 af[2][4];
    #pragma unroll
    for (int s=0;s<2;s++)
      #pragma unroll
      for (int k=0;k<4;k++) af[s][k] = ldf(abuf + (s*16+l15)*ASTR + k*32 + q*8);
    float hsPrev[2][4];
    #pragma unroll
    for (int tt=0; tt<2; tt++){
      int cc = w*32 + tt*16 + l15;
      const unsigned short* bsp = WssT + (size_t)cc*128 + q*8;
      const unsigned short* bcp = WssT + (size_t)(cc+256)*128 + q*8;
      f32x4 aS[2], aC[2];
      aS[0]={0.f,0.f,0.f,0.f}; aS[1]=aS[0]; aC[0]=aS[0]; aC[1]=aS[0];
      #pragma unroll
      for (int k=0;k<4;k++){
        short8 b0 = ldf(bsp + k*32);
        short8 b1 = ldf(bcp + k*32);
        aS[0] = __builtin_amdgcn_mfma_f32_16x16x32_bf16(af[0][k], b0, aS[0],0,0,0);
        aS[1] = __builtin_amdgcn_mfma_f32_16x16x32_bf16(af[1][k], b0, aS[1],0,0,0);
        aC[0] = __builtin_amdgcn_mfma_f32_16x16x32_bf16(af[0][k], b1, aC[0],0,0,0);
        aC[1] = __builtin_amdgcn_mfma_f32_16x16x32_bf16(af[1][k], b1, aC[1],0,0,0);
      }
      float bS = bss[cc], bC = bss[256+cc], qv = qvs[cc];
      float hs[2][4];
      #pragma unroll
      for (int s=0;s<2;s++){
        float4 kv4 = *(const float4*)(kT + ((size_t)(b*256+cc))*128 + ki0 + s*16 + q*4);
        float kvv[4] = {kv4.x, kv4.y, kv4.z, kv4.w};
        #pragma unroll
        for (int r=0;r<4;r++){
          int row = s*16 + q*4 + r;
          float ne = qv*kvv[r]*(1.f + aC[s][r] + bC) + aS[s][r] + bS;
          lbuf[row*LSTR + cc] = f2b(lrelu(ne));
          float vv = ne;
          vv += __shfl_xor(vv,1); vv += __shfl_xor(vv,2);
          vv += __shfl_xor(vv,4); vv += __shfl_xor(vv,8);
          hs[s][r] = vv;
        }
      }
      if (tt == 0){
        #pragma unroll
        for (int s=0;s<2;s++)
          #pragma unroll
          for (int r=0;r<4;r++) hsPrev[s][r] = hs[s][r];
      } else if (l15 == 0){
        #pragma unroll
        for (int s=0;s<2;s++)
          #pragma unroll
          for (int r=0;r<4;r++)
            lgs[w*32 + s*16 + q*4 + r] = hsPrev[s][r] + hs[s][r];
      }
    }
  }
  __syncthreads();
  if (t < 256)
    logitsT[((size_t)(b*8 + (t>>5))*128 + ki0 + (t&31))*128 + qi] = lgs[t] * isd;

  // P2: Weo GEMM (K=256) + residual; wave w owns out-cols [w*16, w*16+16)
  float res[2][4];
  int ec = w*16 + l15;
  {
    f32x4 acc0={0.f,0.f,0.f,0.f}, acc1=acc0;
    #pragma unroll
    for (int k=0;k<8;k++){
      short8 lf0 = ldf(lbuf + l15*LSTR + k*32 + q*8);
      short8 lf1 = ldf(lbuf + (16+l15)*LSTR + k*32 + q*8);
      short8 bf = ldf(WeoT + (size_t)ec*256 + k*32 + q*8);
      acc0 = __builtin_amdgcn_mfma_f32_16x16x32_bf16(lf0, bf, acc0,0,0,0);
      acc1 = __builtin_amdgcn_mfma_f32_16x16x32_bf16(lf1, bf, acc1,0,0,0);
    }
    float bb = beo[ec];
    #pragma unroll
    for (int r=0;r<4;r++){
      res[0][r] = edges[(size_t)(p0 + q*4+r)*128 + ec] + acc0[r] + bb;
      res[1][r] = edges[(size_t)(p0 + 16 + q*4+r)*128 + ec] + acc1[r] + bb;
    }
  }
  #pragma unroll
  for (int s=0;s<2;s++)
    #pragma unroll
    for (int r=0;r<4;r++){
      float ps = res[s][r], p2 = res[s][r]*res[s][r];
      ps += __shfl_xor(ps,1); ps += __shfl_xor(ps,2); ps += __shfl_xor(ps,4); ps += __shfl_xor(ps,8);
      p2 += __shfl_xor(p2,1); p2 += __shfl_xor(p2,2); p2 += __shfl_xor(p2,4); p2 += __shfl_xor(p2,8);
      if (l15 == 0){ redS[s*16+q*4+r][w] = ps; redQ[s*16+q*4+r][w] = p2; }
    }
  __syncthreads();
  if (t < 32){
    float s = 0.f, s2 = 0.f;
    #pragma unroll
    for (int i=0;i<8;i++){ s += redS[t][i]; s2 += redQ[t][i]; }
    float m = s*(1.f/128);
    mrow[t] = m; irow[t] = rsqrtf(s2*(1.f/128) - m*m + 1e-5f);
  }
  __syncthreads();
  #pragma unroll
  for (int s=0;s<2;s++)
    #pragma unroll
    for (int r=0;r<4;r++){
      int row = s*16 + q*4 + r;
      abuf[row*ASTR + ec] = f2b(lrelu((res[s][r] - mrow[row])*irow[row]));
    }
  __syncthreads();

  // P3: We1 GEMM (K=128) -> hbuf (reuse lbuf, ASTR stride)
  unsigned short* hbuf = lbuf;
  {
    f32x4 acc0={0.f,0.f,0.f,0.f}, acc1=acc0;
    #pragma unroll
    for (int k=0;k<4;k++){
      short8 a0 = ldf(abuf + l15*ASTR + k*32 + q*8);
      short8 a1 = ldf(abuf + (16+l15)*ASTR + k*32 + q*8);
      short8 bf = ldf(We1T + (size_t)ec*128 + k*32 + q*8);
      acc0 = __builtin_amdgcn_mfma_f32_16x16x32_bf16(a0, bf, acc0,0,0,0);
      acc1 = __builtin_amdgcn_mfma_f32_16x16x32_bf16(a1, bf, acc1,0,0,0);
    }
    float bb = be1[ec];
    #pragma unroll
    for (int r=0;r<4;r++){
      hbuf[(q*4+r)*ASTR + ec] = f2b(lrelu(acc0[r] + bb));
      hbuf[(16+q*4+r)*ASTR + ec] = f2b(lrelu(acc1[r] + bb));
    }
  }
  __syncthreads();
  // P4: We2 GEMM (K=128) + residual -> out
  {
    f32x4 acc0={0.f,0.f,0.f,0.f}, acc1=acc0;
    #pragma unroll
    for (int k=0;k<4;k++){
      short8 h0 = ldf(hbuf + l15*ASTR + k*32 + q*8);
      short8 h1 = ldf(hbuf + (16+l15)*ASTR + k*32 + q*8);
      short8 bf = ldf(We2T + (size_t)ec*128 + k*32 + q*8);
      acc0 = __builtin_amdgcn_mfma_f32_16x16x32_bf16(h0, bf, acc0,0,0,0);
      acc1 = __builtin_amdgcn_mfma_f32_16x16x32_bf16(h1, bf, acc1,0,0,0);
    }
    float bb = be2[ec];
    #pragma unroll
    for (int r=0;r<4;r++){
      out_edges[(size_t)(p0 + q*4+r)*128 + ec] = res[0][r] + acc0[r] + bb;
      out_edges[(size_t)(p0 + 16 + q*4+r)*128 + ec] = res[1][r] + acc1[r] + bb;
    }
  }
}

// ---- softmax over q axis; bf16 output in [b,h,qi,ki] ----
__global__ void k_softmax(const float* __restrict__ logitsT, unsigned short* __restrict__ attnB){
  int t = threadIdx.x, w = t>>6, l = t&63;
  int row = blockIdx.x*4 + w;          // (b*8+h)*128 + ki
  const float* src = logitsT + (size_t)row*128;
  float x0 = src[l], x1 = src[l+64];
  float mx = fmaxf(x0,x1);
  #pragma unroll
  for (int m=1;m<64;m<<=1) mx = fmaxf(mx, __shfl_xor(mx,m));
  float e0 = expf(x0-mx), e1 = expf(x1-mx);
  float s = e0+e1;
  #pragma unroll
  for (int m=1;m<64;m<<=1) s += __shfl_xor(s,m);
  float inv = 1.f/s;
  int bh = row>>7, ki = row&127;
  attnB[((size_t)bh*128 + l)*128 + ki]    = f2b(e0*inv);
  attnB[((size_t)bh*128 + l+64)*128 + ki] = f2b(e1*inv);
}

// ---- mega node kernel (512 threads): wv -> Wno+res -> film2 -> mlp1 -> mlp2+res ----
#define HSTR 1040
__global__ __launch_bounds__(512) void k_node(
    const unsigned short* __restrict__ attnB, const unsigned short* __restrict__ vT,
    const float* __restrict__ nodes, const float* __restrict__ cond,
    const unsigned short* __restrict__ WnoT, const float* __restrict__ bno,
    const unsigned short* __restrict__ Wn1T, const float* __restrict__ bn1,
    const unsigned short* __restrict__ Wn2T, const float* __restrict__ bn2,
    float* __restrict__ out_nodes){
  __shared__ __align__(16) unsigned short abuf[16*264];
  __shared__ __align__(16) unsigned short hbuf[16*HSTR];
  __shared__ float redS[16][8], redQ[16][8], mrow[16], irow[16];
  int t = threadIdx.x;
  int b = blockIdx.x >> 3, n0 = (blockIdx.x & 7)*16;
  int w = t >> 6, l15 = t & 15, q = (t & 63) >> 4;

  // P0: wv GEMM (K=128); wave w = head w, out-cols [w*32, w*32+32)
  {
    const unsigned short* ap = attnB + ((size_t)(b*8+w)*128 + n0 + l15)*128 + q*8;
    short8 af[4];
    #pragma unroll
    for (int k=0;k<4;k++) af[k] = ldf(ap + k*32);
    #pragma unroll
    for (int tt=0;tt<2;tt++){
      int cc = w*32 + tt*16 + l15;
      const unsigned short* bp = vT + (size_t)(b*256+cc)*128 + q*8;
      f32x4 acc = {0.f,0.f,0.f,0.f};
      #pragma unroll
      for (int k=0;k<4;k++) acc = __builtin_amdgcn_mfma_f32_16x16x32_bf16(af[k], ldf(bp + k*32), acc,0,0,0);
      #pragma unroll
      for (int r=0;r<4;r++) abuf[(q*4+r)*264 + cc] = f2b(acc[r]);
    }
  }
  __syncthreads();

  // P2: Wno GEMM (K=256) + residual; wave w cols [w*32, +32)
  float res[2][4];
  {
    short8 af[8];
    #pragma unroll
    for (int k=0;k<8;k++) af[k] = ldf(abuf + l15*264 + k*32 + q*8);
    #pragma unroll
    for (int tt=0;tt<2;tt++){
      int cc = w*32 + tt*16 + l15;
      const unsigned short* bp = WnoT + (size_t)cc*256 + q*8;
      f32x4 acc = {0.f,0.f,0.f,0.f};
      #pragma unroll
      for (int k=0;k<8;k++) acc = __builtin_amdgcn_mfma_f32_16x16x32_bf16(af[k], ldf(bp + k*32), acc,0,0,0);
      float bb = bno[cc];
      #pragma unroll
      for (int r=0;r<4;r++)
        res[tt][r] = nodes[(size_t)(b*128+n0+q*4+r)*256 + cc] + acc[r] + bb;
    }
  }
  #pragma unroll
  for (int r=0;r<4;r++){
    float ps = res[0][r]+res[1][r];
    float p2 = res[0][r]*res[0][r]+res[1][r]*res[1][r];
    ps += __shfl_xor(ps,1); ps += __shfl_xor(ps,2); ps += __shfl_xor(ps,4); ps += __shfl_xor(ps,8);
    p2 += __shfl_xor(p2,1); p2 += __shfl_xor(p2,2); p2 += __shfl_xor(p2,4); p2 += __shfl_xor(p2,8);
    if (l15 == 0){ redS[q*4+r][w] = ps; redQ[q*4+r][w] = p2; }
  }
  __syncthreads();
  if (t < 16){
    float s = 0.f, s2 = 0.f;
    #pragma unroll
    for (int i=0;i<8;i++){ s += redS[t][i]; s2 += redQ[t][i]; }
    float m = s*(1.f/256);
    mrow[t] = m; irow[t] = rsqrtf(s2*(1.f/256) - m*m + 1e-5f);
  }
  __syncthreads();
  // P4: film2 -> abuf
  #pragma unroll
  for (int tt=0;tt<2;tt++){
    int cc = w*32 + tt*16 + l15;
    float mul = 1.f + cond[b*1024 + 512 + cc];
    float add = cond[b*1024 + 768 + cc];
    #pragma unroll
    for (int r=0;r<4;r++){
      int row = q*4+r;
      abuf[row*264 + cc] = f2b(lrelu((res[tt][r] - mrow[row])*irow[row]*mul + add));
    }
  }
  __syncthreads();
  // P5: mlp1 (K=256 -> 1024); wave w cols [w*128, +128)
  {
    short8 af[8];
    #pragma unroll
    for (int k=0;k<8;k++) af[k] = ldf(abuf + l15*264 + k*32 + q*8);
    #pragma unroll
    for (int tt=0;tt<8;tt++){
      int cc = w*128 + tt*16 + l15;
      const unsigned short* bp = Wn1T + (size_t)cc*256 + q*8;
      f32x4 acc = {0.f,0.f,0.f,0.f};
      #pragma unroll
      for (int k=0;k<8;k++) acc = __builtin_amdgcn_mfma_f32_16x16x32_bf16(af[k], ldf(bp + k*32), acc,0,0,0);
      float bb = bn1[cc];
      #pragma unroll
      for (int r=0;r<4;r++)
        hbuf[(q*4+r)*HSTR + cc] = f2b(lrelu(acc[r] + bb));
    }
  }
  __syncthreads();
  // P6: mlp2 (K=1024 -> 256) + residual
  {
    f32x4 acc2[2];
    acc2[0]={0.f,0.f,0.f,0.f}; acc2[1]=acc2[0];
    for (int k=0;k<32;k++){
      short8 hf = ldf(hbuf + l15*HSTR + k*32 + q*8);
      #pragma unroll
      for (int tt=0;tt<2;tt++){
        int cc = w*32 + tt*16 + l15;
        short8 bf = ldf(Wn2T + (size_t)cc*1024 + k*32 + q*8);
        acc2[tt] = __builtin_amdgcn_mfma_f32_16x16x32_bf16(hf, bf, acc2[tt],0,0,0);
      }
    }
    #pragma unroll
    for (int tt=0;tt<2;tt++){
      int cc = w*32 + tt*16 + l15;
      float bb = bn2[cc];
      #pragma unroll
      for (int r=0;r<4;r++)
        out_nodes[(size_t)(b*128+n0+q*4+r)*256 + cc] = res[tt][r] + acc2[tt][r] + bb;
    }
  }
}

extern "C" void kernel_launch(void* const* d_in, const int* in_sizes, int n_inp,
                              void* d_out, int out_size, void* d_ws, size_t ws_size,
                              hipStream_t stream){
  const float* nodes = (const float*)d_in[0];
  const float* edges = (const float*)d_in[1];
  const float* conds = (const float*)d_in[2];
  const float* Wc   = (const float*)d_in[3];
  const float* bc   = (const float*)d_in[4];
  const float* Wqkv = (const float*)d_in[5];
  const float* bqkv = (const float*)d_in[6];
  const float* Wss  = (const float*)d_in[7];
  const float* bss  = (const float*)d_in[8];
  const float* Wno  = (const float*)d_in[9];
  const float* bno  = (const float*)d_in[10];
  const float* Weo  = (const float*)d_in[11];
  const float* beo  = (const float*)d_in[12];
  const float* Wn1  = (const float*)d_in[13];
  const float* bn1  = (const float*)d_in[14];
  const float* Wn2  = (const float*)d_in[15];
  const float* bn2  = (const float*)d_in[16];
  const float* We1  = (const float*)d_in[17];
  const float* be1  = (const float*)d_in[18];
  const float* We2  = (const float*)d_in[19];
  const float* be2  = (const float*)d_in[20];

  float* ws      = (float*)d_ws;
  float* cond    = ws;                       // 4096
  float* qbuf    = cond + 4096;              // 131072
  float* kT      = qbuf + 131072;            // 131072
  float* logitsT = kT + 131072;              // 524288
  unsigned short* attnB = (unsigned short*)(logitsT + 524288);  // 524288 ushorts
  unsigned short* vT    = attnB + 524288;                        // 131072 ushorts
  unsigned short* wbf   = vT + 131072;                           // 917504 ushorts

  unsigned short* WssT  = wbf;
  unsigned short* WeoT  = wbf + 65536;
  unsigned short* We1T  = wbf + 98304;
  unsigned short* We2T  = wbf + 114688;
  unsigned short* WqkvT = wbf + 131072;
  unsigned short* WnoT  = wbf + 327680;
  unsigned short* Wn1T  = wbf + 393216;
  unsigned short* Wn2T  = wbf + 655360;

  float* out_nodes = (float*)d_out;
  float* out_edges = out_nodes + 131072;

  k_setup<<<912, 256, 0, stream>>>(Wss, Weo, We1, We2, Wqkv, Wno, Wn1, Wn2,
                                   conds, Wc, bc, wbf, cond);
  k_nodeA<<<128, 256, 0, stream>>>(nodes, cond, WqkvT, bqkv, qbuf, kT, vT);
  k_edge<<<BB*NN*NN/32, 512, 0, stream>>>(edges, qbuf, kT, WssT, bss, WeoT, beo,
                                          We1T, be1, We2T, be2, logitsT, out_edges);
  k_softmax<<<BB*NH*NN/4, 256, 0, stream>>>(logitsT, attnB);
  k_node<<<32, 512, 0, stream>>>(attnB, vT, nodes, cond, WnoT, bno, Wn1T, bn1,
                                 Wn2T, bn2, out_nodes);
}

// Round 7
// 257.266 us; speedup vs baseline: 2.5545x; 1.0131x over previous
//
#include <hip/hip_runtime.h>
#include <hip/hip_bf16.h>

#define BB 4
#define NN 128
#define NH 8

typedef __attribute__((ext_vector_type(8))) short short8;
typedef __attribute__((ext_vector_type(4))) float f32x4;

__device__ __forceinline__ float lrelu(float x){ return fmaxf(x, 0.1f*x); }
__device__ __forceinline__ unsigned short f2b(float x){
  __hip_bfloat16 h = __float2bfloat16(x);
  return *reinterpret_cast<unsigned short*>(&h);
}
__device__ __forceinline__ short8 ldf(const unsigned short* p){ return *(const short8*)p; }

// wbf ushort offsets: WssT 0 [512x128] | WeoT 65536 [128x256] | We1T 98304 [128x128]
// We2T 114688 [128x128] | WqkvT 131072 [768x256] | WnoT 327680 [256x256]
// Wn1T 393216 [1024x256] | Wn2T 655360 [256x1024]

// ---- setup: LDS-tiled bf16 transposes (tiles 0..895) + cond GEMM (896..911) ----
__global__ __launch_bounds__(256) void k_setup(
    const float* Wss, const float* Weo, const float* We1, const float* We2,
    const float* Wqkv, const float* Wno, const float* Wn1, const float* Wn2,
    const float* conds, const float* Wc, const float* bc,
    unsigned short* wbf, float* cond){
  __shared__ float tile[32][33];
  __shared__ float c[256];
  int bid = blockIdx.x, t = threadIdx.x;
  if (bid < 896){
    const float* src; int K, N; size_t doff; int tid;
    if      (bid < 64)  { src=Wss;  K=128;  N=512;  doff=0;      tid=bid; }
    else if (bid < 96)  { src=Weo;  K=256;  N=128;  doff=65536;  tid=bid-64; }
    else if (bid < 112) { src=We1;  K=128;  N=128;  doff=98304;  tid=bid-96; }
    else if (bid < 128) { src=We2;  K=128;  N=128;  doff=114688; tid=bid-112; }
    else if (bid < 320) { src=Wqkv; K=256;  N=768;  doff=131072; tid=bid-128; }
    else if (bid < 384) { src=Wno;  K=256;  N=256;  doff=327680; tid=bid-320; }
    else if (bid < 640) { src=Wn1;  K=256;  N=1024; doff=393216; tid=bid-384; }
    else                { src=Wn2;  K=1024; N=256;  doff=655360; tid=bid-640; }
    int ntk = K >> 5;
    int k0 = (tid % ntk) * 32, n0 = (tid / ntk) * 32;
    int r = t >> 3, c4 = (t & 7) * 4;
    float4 v = *(const float4*)(src + (size_t)(k0+r)*N + n0 + c4);
    tile[r][c4+0]=v.x; tile[r][c4+1]=v.y; tile[r][c4+2]=v.z; tile[r][c4+3]=v.w;
    __syncthreads();
    ushort4 o;
    o.x = f2b(tile[c4+0][r]); o.y = f2b(tile[c4+1][r]);
    o.z = f2b(tile[c4+2][r]); o.w = f2b(tile[c4+3][r]);
    *(ushort4*)(wbf + doff + (size_t)(n0+r)*K + k0 + c4) = o;
  } else {
    int i = bid - 896;
    int b = i >> 2, j = (i&3)*256 + t;
    c[t] = conds[(size_t)b*256 + t];
    __syncthreads();
    float acc = bc[j];
    for (int kk = 0; kk < 256; kk++) acc += c[kk]*Wc[(size_t)kk*1024 + j];
    cond[b*1024 + j] = acc;
  }
}

// ---- film1 + qkv (MFMA). 16 rows x 192-col slice per block, grid 128 ----
#define NSTR 260
__global__ __launch_bounds__(256) void k_nodeA(const float* __restrict__ nodes,
    const float* __restrict__ cond, const unsigned short* __restrict__ WqkvT,
    const float* __restrict__ bqkv, float* __restrict__ qbuf,
    float* __restrict__ kT, unsigned short* __restrict__ vT){
  __shared__ float nbuf[16*NSTR];
  __shared__ __align__(16) unsigned short abuf[16*272];
  __shared__ float psum[256], psq[256], mrow[16], irow[16];
  int t = threadIdx.x;
  int rg = blockIdx.x >> 2, slice = blockIdx.x & 3;
  int b = rg >> 3, n0 = (rg & 7)*16;
  int l = t & 63, w = t >> 6, l15 = l & 15, q = l >> 4;

  const float4* src = (const float4*)(nodes + ((size_t)(b*128+n0))*256);
  #pragma unroll
  for (int i = 0; i < 4; i++){
    int f = t + i*256; int r = f >> 6, c4 = f & 63;
    *(float4*)(nbuf + r*NSTR + c4*4) = src[f];
  }
  __syncthreads();
  {
    int r = t >> 4, p = t & 15;
    float s = 0.f, s2 = 0.f;
    #pragma unroll
    for (int i = 0; i < 16; i++){ float v = nbuf[r*NSTR + p + 16*i]; s += v; s2 += v*v; }
    psum[t] = s; psq[t] = s2;
  }
  __syncthreads();
  if (t < 16){
    float s = 0.f, s2 = 0.f;
    #pragma unroll
    for (int i = 0; i < 16; i++){ s += psum[t*16+i]; s2 += psq[t*16+i]; }
    float m = s*(1.f/256);
    mrow[t] = m; irow[t] = rsqrtf(s2*(1.f/256) - m*m + 1e-5f);
  }
  __syncthreads();
  #pragma unroll
  for (int i = 0; i < 16; i++){
    int f = t + i*256; int r = f >> 8, cc = f & 255;
    float x = (nbuf[r*NSTR+cc]-mrow[r])*irow[r]*(1.f+cond[b*1024+cc]) + cond[b*1024+256+cc];
    abuf[r*272+cc] = f2b(lrelu(x));
  }
  __syncthreads();
  short8 af[8];
  #pragma unroll
  for (int k = 0; k < 8; k++) af[k] = ldf(abuf + l15*272 + k*32 + q*8);
  #pragma unroll
  for (int tt = 0; tt < 3; tt++){
    int cc = slice*192 + w*48 + tt*16 + l15;
    const unsigned short* bp = WqkvT + (size_t)cc*256 + q*8;
    f32x4 acc = {0.f,0.f,0.f,0.f};
    #pragma unroll
    for (int k = 0; k < 8; k++) acc = __builtin_amdgcn_mfma_f32_16x16x32_bf16(af[k], ldf(bp + k*32), acc,0,0,0);
    float bb = bqkv[cc];
    if (cc < 256){
      #pragma unroll
      for (int r = 0; r < 4; r++) qbuf[(size_t)(b*128+n0+q*4+r)*256 + cc] = acc[r] + bb;
    } else if (cc < 512){
      float4 kv; kv.x = acc[0]+bb; kv.y = acc[1]+bb; kv.z = acc[2]+bb; kv.w = acc[3]+bb;
      *(float4*)(kT + ((size_t)(b*256 + cc-256))*128 + n0 + q*4) = kv;
    } else {
      ushort4 vv; vv.x = f2b(acc[0]+bb); vv.y = f2b(acc[1]+bb); vv.z = f2b(acc[2]+bb); vv.w = f2b(acc[3]+bb);
      *(ushort4*)(vT + ((size_t)(b*256 + cc-512))*128 + n0 + q*4) = vv;
    }
  }
}

// ---- fused edge path, 256 threads, 32 rows/block, grid 2048 ----
#define ASTR 144
#define LSTR 272
__global__ __launch_bounds__(256) void k_edge(
    const float* __restrict__ edges, const float* __restrict__ qbuf, const float* __restrict__ kT,
    const unsigned short* __restrict__ WssT, const float* __restrict__ bss,
    const unsigned short* __restrict__ WeoT, const float* __restrict__ beo,
    const unsigned short* __restrict__ We1T, const float* __restrict__ be1,
    const unsigned short* __restrict__ We2T, const float* __restrict__ be2,
    float* __restrict__ logitsT, float* __restrict__ out_edges){
  __shared__ __align__(16) unsigned short abuf[32*ASTR];
  __shared__ __align__(16) unsigned short lbuf[32*LSTR];
  __shared__ float qvs[256];
  __shared__ float redS[32][4], redQ[32][4], mrow[32], irow[32];

  int t = threadIdx.x;
  int p0 = blockIdx.x * 32;
  int b  = p0 >> 14, qi = (p0 >> 7) & 127, ki0 = p0 & 127;
  int w = t >> 6, l15 = t & 15, q = (t & 63) >> 4;

  // P0: stage edges + per-row LN (in-register, 32-lane shuffle) -> abuf
  {
    qvs[t] = qbuf[(size_t)(b*128 + qi)*256 + t];
    const float4* src = (const float4*)(edges + (size_t)p0*128);
    #pragma unroll
    for (int i=0;i<4;i++){
      int idx = t + i*256;
      float4 ev = src[idx];
      int r = idx >> 5, c4 = idx & 31;
      float s  = ev.x + ev.y + ev.z + ev.w;
      float s2 = ev.x*ev.x + ev.y*ev.y + ev.z*ev.z + ev.w*ev.w;
      #pragma unroll
      for (int mm=1; mm<32; mm<<=1){ s += __shfl_xor(s,mm); s2 += __shfl_xor(s2,mm); }
      float m = s*(1.f/128);
      float inv = rsqrtf(s2*(1.f/128) - m*m + 1e-5f);
      ushort4 pk;
      pk.x = f2b(lrelu((ev.x - m)*inv)); pk.y = f2b(lrelu((ev.y - m)*inv));
      pk.z = f2b(lrelu((ev.z - m)*inv)); pk.w = f2b(lrelu((ev.w - m)*inv));
      *(ushort4*)(abuf + r*ASTR + c4*4) = pk;
    }
  }
  __syncthreads();

  // P1: ss GEMM; wave w owns heads {2w,2w+1}; per-head ps accumulate, single reduce
  const float isd = 0.17677669529663687f;
  {
    short8 af[2][4];
    #pragma unroll
    for (int s=0;s<2;s++)
      #pragma unroll
      for (int k=0;k<4;k++) af[s][k] = ldf(abuf + (s*16+l15)*ASTR + k*32 + q*8);
    #pragma unroll
    for (int h2=0; h2<2; h2++){
      int h = w*2 + h2;
      float ps[2][4] = {{0.f,0.f,0.f,0.f},{0.f,0.f,0.f,0.f}};
      #pragma unroll
      for (int tt=0; tt<2; tt++){
        int cc = h*32 + tt*16 + l15;
        const unsigned short* bsp = WssT + (size_t)cc*128 + q*8;
        const unsigned short* bcp = WssT + (size_t)(cc+256)*128 + q*8;
        f32x4 aS[2], aC[2];
        aS[0]={0.f,0.f,0.f,0.f}; aS[1]=aS[0]; aC[0]=aS[0]; aC[1]=aS[0];
        #pragma unroll
        for (int k=0;k<4;k++){
          short8 b0 = ldf(bsp + k*32);
          short8 b1 = ldf(bcp + k*32);
          aS[0] = __builtin_amdgcn_mfma_f32_16x16x32_bf16(af[0][k], b0, aS[0],0,0,0);
          aS[1] = __builtin_amdgcn_mfma_f32_16x16x32_bf16(af[1][k], b0, aS[1],0,0,0);
          aC[0] = __builtin_amdgcn_mfma_f32_16x16x32_bf16(af[0][k], b1, aC[0],0,0,0);
          aC[1] = __builtin_amdgcn_mfma_f32_16x16x32_bf16(af[1][k], b1, aC[1],0,0,0);
        }
        float bS = bss[cc], bC = bss[256+cc], qv = qvs[cc];
        #pragma unroll
        for (int s=0;s<2;s++){
          float4 kv4 = *(const float4*)(kT + ((size_t)(b*256+cc))*128 + ki0 + s*16 + q*4);
          float kvv[4] = {kv4.x, kv4.y, kv4.z, kv4.w};
          #pragma unroll
          for (int r=0;r<4;r++){
            int row = s*16 + q*4 + r;
            float ne = qv*kvv[r]*(1.f + aC[s][r] + bC) + aS[s][r] + bS;
            lbuf[row*LSTR + cc] = f2b(lrelu(ne));
            ps[s][r] += ne;
          }
        }
      }
      #pragma unroll
      for (int s=0;s<2;s++)
        #pragma unroll
        for (int r=0;r<4;r++){
          float v = ps[s][r];
          v += __shfl_xor(v,1); v += __shfl_xor(v,2);
          v += __shfl_xor(v,4); v += __shfl_xor(v,8);
          if (l15 == 0){
            int ki = ki0 + s*16 + q*4 + r;
            logitsT[((size_t)(b*8+h)*128 + ki)*128 + qi] = v * isd;
          }
        }
    }
  }
  __syncthreads();

  // P2: Weo GEMM (K=256) + residual; wave w cols [w*32,+32)
  float res[2][2][4];
  {
    f32x4 acc[2][2];
    acc[0][0]={0.f,0.f,0.f,0.f}; acc[0][1]=acc[0][0]; acc[1][0]=acc[0][0]; acc[1][1]=acc[0][0];
    #pragma unroll
    for (int k=0;k<8;k++){
      short8 lf0 = ldf(lbuf + l15*LSTR + k*32 + q*8);
      short8 lf1 = ldf(lbuf + (16+l15)*LSTR + k*32 + q*8);
      #pragma unroll
      for (int tt=0;tt<2;tt++){
        int ec = w*32 + tt*16 + l15;
        short8 bf = ldf(WeoT + (size_t)ec*256 + k*32 + q*8);
        acc[tt][0] = __builtin_amdgcn_mfma_f32_16x16x32_bf16(lf0, bf, acc[tt][0],0,0,0);
        acc[tt][1] = __builtin_amdgcn_mfma_f32_16x16x32_bf16(lf1, bf, acc[tt][1],0,0,0);
      }
    }
    #pragma unroll
    for (int tt=0;tt<2;tt++){
      int ec = w*32 + tt*16 + l15;
      float bb = beo[ec];
      #pragma unroll
      for (int s=0;s<2;s++)
        #pragma unroll
        for (int r=0;r<4;r++){
          int row = s*16 + q*4 + r;
          res[tt][s][r] = edges[(size_t)(p0+row)*128 + ec] + acc[tt][s][r] + bb;
        }
    }
  }
  #pragma unroll
  for (int s=0;s<2;s++)
    #pragma unroll
    for (int r=0;r<4;r++){
      float ps = res[0][s][r] + res[1][s][r];
      float p2 = res[0][s][r]*res[0][s][r] + res[1][s][r]*res[1][s][r];
      ps += __shfl_xor(ps,1); ps += __shfl_xor(ps,2); ps += __shfl_xor(ps,4); ps += __shfl_xor(ps,8);
      p2 += __shfl_xor(p2,1); p2 += __shfl_xor(p2,2); p2 += __shfl_xor(p2,4); p2 += __shfl_xor(p2,8);
      if (l15 == 0){ redS[s*16+q*4+r][w] = ps; redQ[s*16+q*4+r][w] = p2; }
    }
  __syncthreads();
  if (t < 32){
    float s = redS[t][0]+redS[t][1]+redS[t][2]+redS[t][3];
    float s2 = redQ[t][0]+redQ[t][1]+redQ[t][2]+redQ[t][3];
    float m = s*(1.f/128);
    mrow[t] = m; irow[t] = rsqrtf(s2*(1.f/128) - m*m + 1e-5f);
  }
  __syncthreads();
  #pragma unroll
  for (int tt=0;tt<2;tt++){
    int ec = w*32 + tt*16 + l15;
    #pragma unroll
    for (int s=0;s<2;s++)
      #pragma unroll
      for (int r=0;r<4;r++){
        int row = s*16 + q*4 + r;
        abuf[row*ASTR + ec] = f2b(lrelu((res[tt][s][r] - mrow[row])*irow[row]));
      }
  }
  __syncthreads();

  // P3: We1 GEMM (K=128) -> hbuf (reuse lbuf at ASTR stride)
  unsigned short* hbuf = lbuf;
  {
    f32x4 acc[2][2];
    acc[0][0]={0.f,0.f,0.f,0.f}; acc[0][1]=acc[0][0]; acc[1][0]=acc[0][0]; acc[1][1]=acc[0][0];
    #pragma unroll
    for (int k=0;k<4;k++){
      short8 a0 = ldf(abuf + l15*ASTR + k*32 + q*8);
      short8 a1 = ldf(abuf + (16+l15)*ASTR + k*32 + q*8);
      #pragma unroll
      for (int tt=0;tt<2;tt++){
        int ec = w*32 + tt*16 + l15;
        short8 bf = ldf(We1T + (size_t)ec*128 + k*32 + q*8);
        acc[tt][0] = __builtin_amdgcn_mfma_f32_16x16x32_bf16(a0, bf, acc[tt][0],0,0,0);
        acc[tt][1] = __builtin_amdgcn_mfma_f32_16x16x32_bf16(a1, bf, acc[tt][1],0,0,0);
      }
    }
    #pragma unroll
    for (int tt=0;tt<2;tt++){
      int ec = w*32 + tt*16 + l15;
      float bb = be1[ec];
      #pragma unroll
      for (int r=0;r<4;r++){
        hbuf[(q*4+r)*ASTR + ec] = f2b(lrelu(acc[tt][0][r] + bb));
        hbuf[(16+q*4+r)*ASTR + ec] = f2b(lrelu(acc[tt][1][r] + bb));
      }
    }
  }
  __syncthreads();
  // P4: We2 GEMM (K=128) + residual -> out
  {
    f32x4 acc[2][2];
    acc[0][0]={0.f,0.f,0.f,0.f}; acc[0][1]=acc[0][0]; acc[1][0]=acc[0][0]; acc[1][1]=acc[0][0];
    #pragma unroll
    for (int k=0;k<4;k++){
      short8 h0 = ldf(hbuf + l15*ASTR + k*32 + q*8);
      short8 h1 = ldf(hbuf + (16+l15)*ASTR + k*32 + q*8);
      #pragma unroll
      for (int tt=0;tt<2;tt++){
        int ec = w*32 + tt*16 + l15;
        short8 bf = ldf(We2T + (size_t)ec*128 + k*32 + q*8);
        acc[tt][0] = __builtin_amdgcn_mfma_f32_16x16x32_bf16(h0, bf, acc[tt][0],0,0,0);
        acc[tt][1] = __builtin_amdgcn_mfma_f32_16x16x32_bf16(h1, bf, acc[tt][1],0,0,0);
      }
    }
    #pragma unroll
    for (int tt=0;tt<2;tt++){
      int ec = w*32 + tt*16 + l15;
      float bb = be2[ec];
      #pragma unroll
      for (int r=0;r<4;r++){
        out_edges[(size_t)(p0 + q*4+r)*128 + ec] = res[tt][0][r] + acc[tt][0][r] + bb;
        out_edges[(size_t)(p0 + 16 + q*4+r)*128 + ec] = res[tt][1][r] + acc[tt][1][r] + bb;
      }
    }
  }
}

// ---- softmax over q axis, one block per (b,h); coalesced bf16 attn writes ----
__global__ __launch_bounds__(256) void k_attn(const float* __restrict__ logitsT,
                                              unsigned short* __restrict__ attnB){
  __shared__ float tile[32][129];
  __shared__ float mS[128], sS[128];
  int t = threadIdx.x, w = t >> 6, l = t & 63;
  const float* base = logitsT + (size_t)blockIdx.x * 16384;
  for (int i = 0; i < 32; i++){
    int ki = w*32 + i;
    float x0 = base[ki*128 + l], x1 = base[ki*128 + 64 + l];
    float mx = fmaxf(x0, x1);
    #pragma unroll
    for (int m=1;m<64;m<<=1) mx = fmaxf(mx, __shfl_xor(mx,m));
    float s = __expf(x0-mx) + __expf(x1-mx);
    #pragma unroll
    for (int m=1;m<64;m<<=1) s += __shfl_xor(s,m);
    if (l == 0){ mS[ki] = mx; sS[ki] = 1.f/s; }
  }
  __syncthreads();
  unsigned short* obase = attnB + (size_t)blockIdx.x * 16384;
  for (int c = 0; c < 4; c++){
    int q0 = c*32;
    #pragma unroll
    for (int i = 0; i < 16; i++){
      int idx = t + i*256; int ki = idx >> 5, qq = idx & 31;
      tile[qq][ki] = base[ki*128 + q0 + qq];
    }
    __syncthreads();
    #pragma unroll
    for (int i = 0; i < 16; i++){
      int idx = t + i*256; int qq = idx >> 7, ki = idx & 127;
      obase[(q0+qq)*128 + ki] = f2b(__expf(tile[qq][ki] - mS[ki]) * sS[ki]);
    }
    __syncthreads();
  }
}

// ---- nodeB (grid 128 = 32 rowgroups x 4 slices): wv->Wno+res->film2->mlp1 slice ----
#define AB 272
__global__ __launch_bounds__(256) void k_nodeB(
    const unsigned short* __restrict__ attnB, const unsigned short* __restrict__ vT,
    const float* __restrict__ nodes, const float* __restrict__ cond,
    const unsigned short* __restrict__ WnoT, const float* __restrict__ bno,
    const unsigned short* __restrict__ Wn1T, const float* __restrict__ bn1,
    float* __restrict__ nodes1ws, unsigned short* __restrict__ hiddenB){
  __shared__ __align__(16) unsigned short abuf[16*AB];
  __shared__ float redS[16][4], redQ[16][4], mrow[16], irow[16];
  int t = threadIdx.x;
  int rg = blockIdx.x >> 2, slice = blockIdx.x & 3;
  int b = rg >> 3, n0 = (rg & 7)*16;
  int w = t >> 6, l15 = t & 15, q = (t & 63) >> 4;

  // P0: wv (K=128), wave w -> heads {2w,2w+1}, cols [w*64,+64)
  #pragma unroll
  for (int h2=0; h2<2; h2++){
    int h = w*2 + h2;
    const unsigned short* ap = attnB + ((size_t)(b*8+h)*128 + n0 + l15)*128 + q*8;
    short8 af[4];
    #pragma unroll
    for (int k=0;k<4;k++) af[k] = ldf(ap + k*32);
    #pragma unroll
    for (int tt=0;tt<2;tt++){
      int cc = h*32 + tt*16 + l15;
      const unsigned short* bp = vT + (size_t)(b*256+cc)*128 + q*8;
      f32x4 acc = {0.f,0.f,0.f,0.f};
      #pragma unroll
      for (int k=0;k<4;k++) acc = __builtin_amdgcn_mfma_f32_16x16x32_bf16(af[k], ldf(bp + k*32), acc,0,0,0);
      #pragma unroll
      for (int r=0;r<4;r++) abuf[(q*4+r)*AB + cc] = f2b(acc[r]);
    }
  }
  __syncthreads();

  // P1: Wno (K=256) + residual
  float res[4][4];
  {
    short8 aw[8];
    #pragma unroll
    for (int k=0;k<8;k++) aw[k] = ldf(abuf + l15*AB + k*32 + q*8);
    #pragma unroll
    for (int tt=0;tt<4;tt++){
      int cc = w*64 + tt*16 + l15;
      const unsigned short* bp = WnoT + (size_t)cc*256 + q*8;
      f32x4 acc = {0.f,0.f,0.f,0.f};
      #pragma unroll
      for (int k=0;k<8;k++) acc = __builtin_amdgcn_mfma_f32_16x16x32_bf16(aw[k], ldf(bp + k*32), acc,0,0,0);
      float bb = bno[cc];
      #pragma unroll
      for (int r=0;r<4;r++)
        res[tt][r] = nodes[(size_t)(b*128+n0+q*4+r)*256 + cc] + acc[r] + bb;
    }
  }
  #pragma unroll
  for (int r=0;r<4;r++){
    float ps = res[0][r]+res[1][r]+res[2][r]+res[3][r];
    float p2 = res[0][r]*res[0][r]+res[1][r]*res[1][r]+res[2][r]*res[2][r]+res[3][r]*res[3][r];
    ps += __shfl_xor(ps,1); ps += __shfl_xor(ps,2); ps += __shfl_xor(ps,4); ps += __shfl_xor(ps,8);
    p2 += __shfl_xor(p2,1); p2 += __shfl_xor(p2,2); p2 += __shfl_xor(p2,4); p2 += __shfl_xor(p2,8);
    if (l15 == 0){ redS[q*4+r][w] = ps; redQ[q*4+r][w] = p2; }
  }
  __syncthreads();
  if (t < 16){
    float s = redS[t][0]+redS[t][1]+redS[t][2]+redS[t][3];
    float s2 = redQ[t][0]+redQ[t][1]+redQ[t][2]+redQ[t][3];
    float m = s*(1.f/256);
    mrow[t] = m; irow[t] = rsqrtf(s2*(1.f/256) - m*m + 1e-5f);
  }
  __syncthreads();
  // film2 -> abuf; slice 0 stores nodes1
  #pragma unroll
  for (int tt=0;tt<4;tt++){
    int cc = w*64 + tt*16 + l15;
    float mul = 1.f + cond[b*1024 + 512 + cc];
    float add = cond[b*1024 + 768 + cc];
    #pragma unroll
    for (int r=0;r<4;r++){
      int row = q*4+r;
      abuf[row*AB + cc] = f2b(lrelu((res[tt][r] - mrow[row])*irow[row]*mul + add));
    }
  }
  if (slice == 0){
    #pragma unroll
    for (int tt=0;tt<4;tt++){
      int cc = w*64 + tt*16 + l15;
      #pragma unroll
      for (int r=0;r<4;r++)
        nodes1ws[(size_t)(rg*16 + q*4+r)*256 + cc] = res[tt][r];
    }
  }
  __syncthreads();
  // P2: mlp1 slice (K=256 -> 256 cols of 1024)
  {
    short8 a2[8];
    #pragma unroll
    for (int k=0;k<8;k++) a2[k] = ldf(abuf + l15*AB + k*32 + q*8);
    #pragma unroll
    for (int tt=0;tt<4;tt++){
      int cc = slice*256 + w*64 + tt*16 + l15;
      const unsigned short* bp = Wn1T + (size_t)cc*256 + q*8;
      f32x4 acc = {0.f,0.f,0.f,0.f};
      #pragma unroll
      for (int k=0;k<8;k++) acc = __builtin_amdgcn_mfma_f32_16x16x32_bf16(a2[k], ldf(bp + k*32), acc,0,0,0);
      float bb = bn1[cc];
      #pragma unroll
      for (int r=0;r<4;r++)
        hiddenB[((size_t)rg*16 + q*4+r)*1024 + cc] = f2b(lrelu(acc[r] + bb));
    }
  }
}

// ---- nodeC (grid 128 = 32 rowgroups x 4 col-slices): mlp2 (K=1024) + residual ----
__global__ __launch_bounds__(256) void k_nodeC(
    const unsigned short* __restrict__ hiddenB, const float* __restrict__ nodes1ws,
    const unsigned short* __restrict__ Wn2T, const float* __restrict__ bn2,
    float* __restrict__ out_nodes){
  int t = threadIdx.x;
  int rg = blockIdx.x >> 2, cs = blockIdx.x & 3;
  int w = t >> 6, l15 = t & 15, q = (t & 63) >> 4;
  int cc = cs*64 + w*16 + l15;
  const unsigned short* ap = hiddenB + ((size_t)rg*16 + l15)*1024 + q*8;
  const unsigned short* bp = Wn2T + (size_t)cc*1024 + q*8;
  f32x4 acc = {0.f,0.f,0.f,0.f};
  #pragma unroll
  for (int k=0;k<32;k++)
    acc = __builtin_amdgcn_mfma_f32_16x16x32_bf16(ldf(ap + k*32), ldf(bp + k*32), acc,0,0,0);
  float bb = bn2[cc];
  #pragma unroll
  for (int r=0;r<4;r++){
    size_t row = (size_t)rg*16 + q*4 + r;
    out_nodes[row*256 + cc] = nodes1ws[row*256 + cc] + acc[r] + bb;
  }
}

extern "C" void kernel_launch(void* const* d_in, const int* in_sizes, int n_inp,
                              void* d_out, int out_size, void* d_ws, size_t ws_size,
                              hipStream_t stream){
  const float* nodes = (const float*)d_in[0];
  const float* edges = (const float*)d_in[1];
  const float* conds = (const float*)d_in[2];
  const float* Wc   = (const float*)d_in[3];
  const float* bc   = (const float*)d_in[4];
  const float* Wqkv = (const float*)d_in[5];
  const float* bqkv = (const float*)d_in[6];
  const float* Wss  = (const float*)d_in[7];
  const float* bss  = (const float*)d_in[8];
  const float* Wno  = (const float*)d_in[9];
  const float* bno  = (const float*)d_in[10];
  const float* Weo  = (const float*)d_in[11];
  const float* beo  = (const float*)d_in[12];
  const float* Wn1  = (const float*)d_in[13];
  const float* bn1  = (const float*)d_in[14];
  const float* Wn2  = (const float*)d_in[15];
  const float* bn2  = (const float*)d_in[16];
  const float* We1  = (const float*)d_in[17];
  const float* be1  = (const float*)d_in[18];
  const float* We2  = (const float*)d_in[19];
  const float* be2  = (const float*)d_in[20];

  float* ws       = (float*)d_ws;
  float* cond     = ws;                       // 4096
  float* qbuf     = cond + 4096;              // 131072
  float* kT       = qbuf + 131072;            // 131072
  float* logitsT  = kT + 131072;              // 524288
  float* nodes1ws = logitsT + 524288;         // 131072
  unsigned short* attnB   = (unsigned short*)(nodes1ws + 131072); // 524288 us
  unsigned short* vT      = attnB + 524288;                       // 131072 us
  unsigned short* hiddenB = vT + 131072;                          // 524288 us
  unsigned short* wbf     = hiddenB + 524288;                     // 917504 us

  unsigned short* WssT  = wbf;
  unsigned short* WeoT  = wbf + 65536;
  unsigned short* We1T  = wbf + 98304;
  unsigned short* We2T  = wbf + 114688;
  unsigned short* WqkvT = wbf + 131072;
  unsigned short* WnoT  = wbf + 327680;
  unsigned short* Wn1T  = wbf + 393216;
  unsigned short* Wn2T  = wbf + 655360;

  float* out_nodes = (float*)d_out;
  float* out_edges = out_nodes + 131072;

  k_setup<<<912, 256, 0, stream>>>(Wss, Weo, We1, We2, Wqkv, Wno, Wn1, Wn2,
                                   conds, Wc, bc, wbf, cond);
  k_nodeA<<<128, 256, 0, stream>>>(nodes, cond, WqkvT, bqkv, qbuf, kT, vT);
  k_edge<<<BB*NN*NN/32, 256, 0, stream>>>(edges, qbuf, kT, WssT, bss, WeoT, beo,
                                          We1T, be1, We2T, be2, logitsT, out_edges);
  k_attn<<<BB*NH, 256, 0, stream>>>(logitsT, attnB);
  k_nodeB<<<128, 256, 0, stream>>>(attnB, vT, nodes, cond, WnoT, bno, Wn1T, bn1,
                                   nodes1ws, hiddenB);
  k_nodeC<<<128, 256, 0, stream>>>(hiddenB, nodes1ws, Wn2T, bn2, out_nodes);
}

// Round 8
// 218.677 us; speedup vs baseline: 3.0053x; 1.1765x over previous
//
#include <hip/hip_runtime.h>
#include <hip/hip_bf16.h>

#define BB 4
#define NN 128
#define NH 8

typedef __attribute__((ext_vector_type(8))) short short8;
typedef __attribute__((ext_vector_type(4))) float f32x4;

__device__ __forceinline__ float lrelu(float x){ return fmaxf(x, 0.1f*x); }
__device__ __forceinline__ unsigned short f2b(float x){
  __hip_bfloat16 h = __float2bfloat16(x);
  return *reinterpret_cast<unsigned short*>(&h);
}
__device__ __forceinline__ short8 ldf(const unsigned short* p){ return *(const short8*)p; }

// wbf ushort offsets: WssT 0 [512x128] | WeoT 65536 [128x256] | We1T 98304 [128x128]
// We2T 114688 [128x128] | WqkvT 131072 [768x256] | WnoT 327680 [256x256]
// Wn1T 393216 [1024x256] | Wn2T 655360 [256x1024]

// ---- setup: LDS-tiled bf16 transposes (tiles 0..895) + cond GEMM (896..911) ----
__global__ __launch_bounds__(256) void k_setup(
    const float* Wss, const float* Weo, const float* We1, const float* We2,
    const float* Wqkv, const float* Wno, const float* Wn1, const float* Wn2,
    const float* conds, const float* Wc, const float* bc,
    unsigned short* wbf, float* cond){
  __shared__ float tile[32][33];
  __shared__ float c[256];
  int bid = blockIdx.x, t = threadIdx.x;
  if (bid < 896){
    const float* src; int K, N; size_t doff; int tid;
    if      (bid < 64)  { src=Wss;  K=128;  N=512;  doff=0;      tid=bid; }
    else if (bid < 96)  { src=Weo;  K=256;  N=128;  doff=65536;  tid=bid-64; }
    else if (bid < 112) { src=We1;  K=128;  N=128;  doff=98304;  tid=bid-96; }
    else if (bid < 128) { src=We2;  K=128;  N=128;  doff=114688; tid=bid-112; }
    else if (bid < 320) { src=Wqkv; K=256;  N=768;  doff=131072; tid=bid-128; }
    else if (bid < 384) { src=Wno;  K=256;  N=256;  doff=327680; tid=bid-320; }
    else if (bid < 640) { src=Wn1;  K=256;  N=1024; doff=393216; tid=bid-384; }
    else                { src=Wn2;  K=1024; N=256;  doff=655360; tid=bid-640; }
    int ntk = K >> 5;
    int k0 = (tid % ntk) * 32, n0 = (tid / ntk) * 32;
    int r = t >> 3, c4 = (t & 7) * 4;
    float4 v = *(const float4*)(src + (size_t)(k0+r)*N + n0 + c4);
    tile[r][c4+0]=v.x; tile[r][c4+1]=v.y; tile[r][c4+2]=v.z; tile[r][c4+3]=v.w;
    __syncthreads();
    ushort4 o;
    o.x = f2b(tile[c4+0][r]); o.y = f2b(tile[c4+1][r]);
    o.z = f2b(tile[c4+2][r]); o.w = f2b(tile[c4+3][r]);
    *(ushort4*)(wbf + doff + (size_t)(n0+r)*K + k0 + c4) = o;
  } else {
    int i = bid - 896;
    int b = i >> 2, j = (i&3)*256 + t;
    c[t] = conds[(size_t)b*256 + t];
    __syncthreads();
    float acc = bc[j];
    for (int kk = 0; kk < 256; kk++) acc += c[kk]*Wc[(size_t)kk*1024 + j];
    cond[b*1024 + j] = acc;
  }
}

// ---- film1 + qkv (MFMA). 16 rows x 192-col slice per block, grid 128 ----
#define NSTR 260
__global__ __launch_bounds__(256) void k_nodeA(const float* __restrict__ nodes,
    const float* __restrict__ cond, const unsigned short* __restrict__ WqkvT,
    const float* __restrict__ bqkv, float* __restrict__ qbuf,
    float* __restrict__ kT, unsigned short* __restrict__ vT){
  __shared__ float nbuf[16*NSTR];
  __shared__ __align__(16) unsigned short abuf[16*272];
  __shared__ float psum[256], psq[256], mrow[16], irow[16];
  int t = threadIdx.x;
  int rg = blockIdx.x >> 2, slice = blockIdx.x & 3;
  int b = rg >> 3, n0 = (rg & 7)*16;
  int l = t & 63, w = t >> 6, l15 = l & 15, q = l >> 4;

  const float4* src = (const float4*)(nodes + ((size_t)(b*128+n0))*256);
  #pragma unroll
  for (int i = 0; i < 4; i++){
    int f = t + i*256; int r = f >> 6, c4 = f & 63;
    *(float4*)(nbuf + r*NSTR + c4*4) = src[f];
  }
  __syncthreads();
  {
    int r = t >> 4, p = t & 15;
    float s = 0.f, s2 = 0.f;
    #pragma unroll
    for (int i = 0; i < 16; i++){ float v = nbuf[r*NSTR + p + 16*i]; s += v; s2 += v*v; }
    psum[t] = s; psq[t] = s2;
  }
  __syncthreads();
  if (t < 16){
    float s = 0.f, s2 = 0.f;
    #pragma unroll
    for (int i = 0; i < 16; i++){ s += psum[t*16+i]; s2 += psq[t*16+i]; }
    float m = s*(1.f/256);
    mrow[t] = m; irow[t] = rsqrtf(s2*(1.f/256) - m*m + 1e-5f);
  }
  __syncthreads();
  #pragma unroll
  for (int i = 0; i < 16; i++){
    int f = t + i*256; int r = f >> 8, cc = f & 255;
    float x = (nbuf[r*NSTR+cc]-mrow[r])*irow[r]*(1.f+cond[b*1024+cc]) + cond[b*1024+256+cc];
    abuf[r*272+cc] = f2b(lrelu(x));
  }
  __syncthreads();
  short8 af[8];
  #pragma unroll
  for (int k = 0; k < 8; k++) af[k] = ldf(abuf + l15*272 + k*32 + q*8);
  #pragma unroll
  for (int tt = 0; tt < 3; tt++){
    int cc = slice*192 + w*48 + tt*16 + l15;
    const unsigned short* bp = WqkvT + (size_t)cc*256 + q*8;
    f32x4 acc = {0.f,0.f,0.f,0.f};
    #pragma unroll
    for (int k = 0; k < 8; k++) acc = __builtin_amdgcn_mfma_f32_16x16x32_bf16(af[k], ldf(bp + k*32), acc,0,0,0);
    float bb = bqkv[cc];
    if (cc < 256){
      #pragma unroll
      for (int r = 0; r < 4; r++) qbuf[(size_t)(b*128+n0+q*4+r)*256 + cc] = acc[r] + bb;
    } else if (cc < 512){
      float4 kv; kv.x = acc[0]+bb; kv.y = acc[1]+bb; kv.z = acc[2]+bb; kv.w = acc[3]+bb;
      *(float4*)(kT + ((size_t)(b*256 + cc-256))*128 + n0 + q*4) = kv;
    } else {
      ushort4 vv; vv.x = f2b(acc[0]+bb); vv.y = f2b(acc[1]+bb); vv.z = f2b(acc[2]+bb); vv.w = f2b(acc[3]+bb);
      *(ushort4*)(vT + ((size_t)(b*256 + cc-512))*128 + n0 + q*4) = vv;
    }
  }
}

// ---- fused edge path, 256 threads, 64 rows/block, grid 1024 ----
#define ASTR 144
#define LSTR 264
__global__ __launch_bounds__(256) void k_edge(
    const float* __restrict__ edges, const float* __restrict__ qbuf, const float* __restrict__ kT,
    const unsigned short* __restrict__ WssT, const float* __restrict__ bss,
    const unsigned short* __restrict__ WeoT, const float* __restrict__ beo,
    const unsigned short* __restrict__ We1T, const float* __restrict__ be1,
    const unsigned short* __restrict__ We2T, const float* __restrict__ be2,
    float* __restrict__ logitsT, float* __restrict__ out_edges){
  __shared__ __align__(16) unsigned short abuf[64*ASTR];   // 18432 B
  __shared__ __align__(16) unsigned short lbuf[64*LSTR];   // 33792 B
  __shared__ float qvs[256];
  __shared__ float redS[64][4], redQ[64][4], mrow[64], irow[64];

  int t = threadIdx.x;
  int p0 = blockIdx.x * 64;
  int b  = p0 >> 14, qi = (p0 >> 7) & 127, ki0 = p0 & 127;   // ki0 in {0,64}
  int w = t >> 6, l15 = t & 15, q = (t & 63) >> 4;

  // P0: stage 64x128 edges + per-row LN (32-lane shuffle) -> abuf
  {
    qvs[t] = qbuf[(size_t)(b*128 + qi)*256 + t];
    const float4* src = (const float4*)(edges + (size_t)p0*128);
    #pragma unroll
    for (int i=0;i<8;i++){
      int idx = t + i*256;
      float4 ev = src[idx];
      int r = idx >> 5, c4 = idx & 31;
      float s  = ev.x + ev.y + ev.z + ev.w;
      float s2 = ev.x*ev.x + ev.y*ev.y + ev.z*ev.z + ev.w*ev.w;
      #pragma unroll
      for (int mm=1; mm<32; mm<<=1){ s += __shfl_xor(s,mm); s2 += __shfl_xor(s2,mm); }
      float m = s*(1.f/128);
      float inv = rsqrtf(s2*(1.f/128) - m*m + 1e-5f);
      ushort4 pk;
      pk.x = f2b(lrelu((ev.x - m)*inv)); pk.y = f2b(lrelu((ev.y - m)*inv));
      pk.z = f2b(lrelu((ev.z - m)*inv)); pk.w = f2b(lrelu((ev.w - m)*inv));
      *(ushort4*)(abuf + r*ASTR + c4*4) = pk;
    }
  }
  __syncthreads();

  // P1: ss GEMM; wave w owns heads {2w,2w+1}; 4 row-strips share every B-frag
  const float isd = 0.17677669529663687f;
  {
    short8 af[4][4];
    #pragma unroll
    for (int s=0;s<4;s++)
      #pragma unroll
      for (int k=0;k<4;k++) af[s][k] = ldf(abuf + (s*16+l15)*ASTR + k*32 + q*8);
    #pragma unroll
    for (int h2=0; h2<2; h2++){
      int h = w*2 + h2;
      float ps[4][4] = {{0,0,0,0},{0,0,0,0},{0,0,0,0},{0,0,0,0}};
      #pragma unroll
      for (int tt=0; tt<2; tt++){
        int cc = h*32 + tt*16 + l15;
        const unsigned short* bsp = WssT + (size_t)cc*128 + q*8;
        const unsigned short* bcp = WssT + (size_t)(cc+256)*128 + q*8;
        f32x4 aS[4], aC[4];
        #pragma unroll
        for (int s=0;s<4;s++){ aS[s]={0.f,0.f,0.f,0.f}; aC[s]={0.f,0.f,0.f,0.f}; }
        #pragma unroll
        for (int k=0;k<4;k++){
          short8 b0 = ldf(bsp + k*32);
          short8 b1 = ldf(bcp + k*32);
          #pragma unroll
          for (int s=0;s<4;s++){
            aS[s] = __builtin_amdgcn_mfma_f32_16x16x32_bf16(af[s][k], b0, aS[s],0,0,0);
            aC[s] = __builtin_amdgcn_mfma_f32_16x16x32_bf16(af[s][k], b1, aC[s],0,0,0);
          }
        }
        float bS = bss[cc], bC = bss[256+cc], qv = qvs[cc];
        #pragma unroll
        for (int s=0;s<4;s++){
          float4 kv4 = *(const float4*)(kT + ((size_t)(b*256+cc))*128 + ki0 + s*16 + q*4);
          float kvv[4] = {kv4.x, kv4.y, kv4.z, kv4.w};
          #pragma unroll
          for (int r=0;r<4;r++){
            int row = s*16 + q*4 + r;
            float ne = qv*kvv[r]*(1.f + aC[s][r] + bC) + aS[s][r] + bS;
            lbuf[row*LSTR + cc] = f2b(lrelu(ne));
            ps[s][r] += ne;
          }
        }
      }
      #pragma unroll
      for (int s=0;s<4;s++)
        #pragma unroll
        for (int r=0;r<4;r++){
          float v = ps[s][r];
          v += __shfl_xor(v,1); v += __shfl_xor(v,2);
          v += __shfl_xor(v,4); v += __shfl_xor(v,8);
          if (l15 == 0){
            int ki = ki0 + s*16 + q*4 + r;
            logitsT[((size_t)(b*8+h)*128 + ki)*128 + qi] = v * isd;
          }
        }
    }
  }
  __syncthreads();

  // P2: Weo GEMM (K=256) + residual; wave w cols [w*32,+32), 4 strips
  float res[2][4][4];
  {
    f32x4 acc[2][4];
    #pragma unroll
    for (int tt=0;tt<2;tt++)
      #pragma unroll
      for (int s=0;s<4;s++) acc[tt][s] = {0.f,0.f,0.f,0.f};
    #pragma unroll
    for (int k=0;k<8;k++){
      short8 lf[4];
      #pragma unroll
      for (int s=0;s<4;s++) lf[s] = ldf(lbuf + (s*16+l15)*LSTR + k*32 + q*8);
      #pragma unroll
      for (int tt=0;tt<2;tt++){
        int ec = w*32 + tt*16 + l15;
        short8 bf = ldf(WeoT + (size_t)ec*256 + k*32 + q*8);
        #pragma unroll
        for (int s=0;s<4;s++)
          acc[tt][s] = __builtin_amdgcn_mfma_f32_16x16x32_bf16(lf[s], bf, acc[tt][s],0,0,0);
      }
    }
    #pragma unroll
    for (int tt=0;tt<2;tt++){
      int ec = w*32 + tt*16 + l15;
      float bb = beo[ec];
      #pragma unroll
      for (int s=0;s<4;s++)
        #pragma unroll
        for (int r=0;r<4;r++){
          int row = s*16 + q*4 + r;
          res[tt][s][r] = edges[(size_t)(p0+row)*128 + ec] + acc[tt][s][r] + bb;
        }
    }
  }
  #pragma unroll
  for (int s=0;s<4;s++)
    #pragma unroll
    for (int r=0;r<4;r++){
      float ps = res[0][s][r] + res[1][s][r];
      float p2 = res[0][s][r]*res[0][s][r] + res[1][s][r]*res[1][s][r];
      ps += __shfl_xor(ps,1); ps += __shfl_xor(ps,2); ps += __shfl_xor(ps,4); ps += __shfl_xor(ps,8);
      p2 += __shfl_xor(p2,1); p2 += __shfl_xor(p2,2); p2 += __shfl_xor(p2,4); p2 += __shfl_xor(p2,8);
      if (l15 == 0){ redS[s*16+q*4+r][w] = ps; redQ[s*16+q*4+r][w] = p2; }
    }
  __syncthreads();
  if (t < 64){
    float s = redS[t][0]+redS[t][1]+redS[t][2]+redS[t][3];
    float s2 = redQ[t][0]+redQ[t][1]+redQ[t][2]+redQ[t][3];
    float m = s*(1.f/128);
    mrow[t] = m; irow[t] = rsqrtf(s2*(1.f/128) - m*m + 1e-5f);
  }
  __syncthreads();
  #pragma unroll
  for (int tt=0;tt<2;tt++){
    int ec = w*32 + tt*16 + l15;
    #pragma unroll
    for (int s=0;s<4;s++)
      #pragma unroll
      for (int r=0;r<4;r++){
        int row = s*16 + q*4 + r;
        abuf[row*ASTR + ec] = f2b(lrelu((res[tt][s][r] - mrow[row])*irow[row]));
      }
  }
  __syncthreads();

  // P3: We1 GEMM (K=128) -> hbuf (reuse lbuf at ASTR stride)
  unsigned short* hbuf = lbuf;
  {
    f32x4 acc[2][4];
    #pragma unroll
    for (int tt=0;tt<2;tt++)
      #pragma unroll
      for (int s=0;s<4;s++) acc[tt][s] = {0.f,0.f,0.f,0.f};
    #pragma unroll
    for (int k=0;k<4;k++){
      short8 af2[4];
      #pragma unroll
      for (int s=0;s<4;s++) af2[s] = ldf(abuf + (s*16+l15)*ASTR + k*32 + q*8);
      #pragma unroll
      for (int tt=0;tt<2;tt++){
        int ec = w*32 + tt*16 + l15;
        short8 bf = ldf(We1T + (size_t)ec*128 + k*32 + q*8);
        #pragma unroll
        for (int s=0;s<4;s++)
          acc[tt][s] = __builtin_amdgcn_mfma_f32_16x16x32_bf16(af2[s], bf, acc[tt][s],0,0,0);
      }
    }
    #pragma unroll
    for (int tt=0;tt<2;tt++){
      int ec = w*32 + tt*16 + l15;
      float bb = be1[ec];
      #pragma unroll
      for (int s=0;s<4;s++)
        #pragma unroll
        for (int r=0;r<4;r++)
          hbuf[(s*16+q*4+r)*ASTR + ec] = f2b(lrelu(acc[tt][s][r] + bb));
    }
  }
  __syncthreads();
  // P4: We2 GEMM (K=128) + residual -> out
  {
    f32x4 acc[2][4];
    #pragma unroll
    for (int tt=0;tt<2;tt++)
      #pragma unroll
      for (int s=0;s<4;s++) acc[tt][s] = {0.f,0.f,0.f,0.f};
    #pragma unroll
    for (int k=0;k<4;k++){
      short8 hf[4];
      #pragma unroll
      for (int s=0;s<4;s++) hf[s] = ldf(hbuf + (s*16+l15)*ASTR + k*32 + q*8);
      #pragma unroll
      for (int tt=0;tt<2;tt++){
        int ec = w*32 + tt*16 + l15;
        short8 bf = ldf(We2T + (size_t)ec*128 + k*32 + q*8);
        #pragma unroll
        for (int s=0;s<4;s++)
          acc[tt][s] = __builtin_amdgcn_mfma_f32_16x16x32_bf16(hf[s], bf, acc[tt][s],0,0,0);
      }
    }
    #pragma unroll
    for (int tt=0;tt<2;tt++){
      int ec = w*32 + tt*16 + l15;
      float bb = be2[ec];
      #pragma unroll
      for (int s=0;s<4;s++)
        #pragma unroll
        for (int r=0;r<4;r++){
          int row = s*16 + q*4 + r;
          out_edges[(size_t)(p0+row)*128 + ec] = res[tt][s][r] + acc[tt][s][r] + bb;
        }
    }
  }
}

// ---- softmax over q axis; grid 256 = (b,h) x 8 ki-slices; coalesced bf16 writes ----
__global__ __launch_bounds__(256) void k_attn(const float* __restrict__ logitsT,
                                              unsigned short* __restrict__ attnB){
  __shared__ float tile[16][132];
  __shared__ float mS[16], sS[16];
  int bh = blockIdx.x >> 3, slice = blockIdx.x & 7;
  int t = threadIdx.x, w = t >> 6, l = t & 63;
  const float* base = logitsT + (size_t)bh*16384 + slice*16*128;
  #pragma unroll
  for (int i = 0; i < 8; i++){
    int idx = t + i*256; int ki = idx >> 7, qq = idx & 127;
    tile[ki][qq] = base[ki*128 + qq];
  }
  __syncthreads();
  #pragma unroll
  for (int i = 0; i < 4; i++){
    int ki = w*4 + i;
    float x0 = tile[ki][l], x1 = tile[ki][l+64];
    float mx = fmaxf(x0, x1);
    #pragma unroll
    for (int m=1;m<64;m<<=1) mx = fmaxf(mx, __shfl_xor(mx,m));
    float s = __expf(x0-mx) + __expf(x1-mx);
    #pragma unroll
    for (int m=1;m<64;m<<=1) s += __shfl_xor(s,m);
    if (l == 0){ mS[ki] = mx; sS[ki] = 1.f/s; }
  }
  __syncthreads();
  unsigned short* obase = attnB + (size_t)bh*16384 + slice*16;
  #pragma unroll
  for (int i = 0; i < 8; i++){
    int idx = t + i*256; int qq = idx >> 4, kk = idx & 15;
    obase[qq*128 + kk] = f2b(__expf(tile[kk][qq] - mS[kk]) * sS[kk]);
  }
}

// ---- nodeB (grid 128 = 32 rowgroups x 4 slices): wv->Wno+res->film2->mlp1 slice ----
#define AB 272
__global__ __launch_bounds__(256) void k_nodeB(
    const unsigned short* __restrict__ attnB, const unsigned short* __restrict__ vT,
    const float* __restrict__ nodes, const float* __restrict__ cond,
    const unsigned short* __restrict__ WnoT, const float* __restrict__ bno,
    const unsigned short* __restrict__ Wn1T, const float* __restrict__ bn1,
    float* __restrict__ nodes1ws, unsigned short* __restrict__ hiddenB){
  __shared__ __align__(16) unsigned short abuf[16*AB];
  __shared__ float redS[16][4], redQ[16][4], mrow[16], irow[16];
  int t = threadIdx.x;
  int rg = blockIdx.x >> 2, slice = blockIdx.x & 3;
  int b = rg >> 3, n0 = (rg & 7)*16;
  int w = t >> 6, l15 = t & 15, q = (t & 63) >> 4;

  #pragma unroll
  for (int h2=0; h2<2; h2++){
    int h = w*2 + h2;
    const unsigned short* ap = attnB + ((size_t)(b*8+h)*128 + n0 + l15)*128 + q*8;
    short8 af[4];
    #pragma unroll
    for (int k=0;k<4;k++) af[k] = ldf(ap + k*32);
    #pragma unroll
    for (int tt=0;tt<2;tt++){
      int cc = h*32 + tt*16 + l15;
      const unsigned short* bp = vT + (size_t)(b*256+cc)*128 + q*8;
      f32x4 acc = {0.f,0.f,0.f,0.f};
      #pragma unroll
      for (int k=0;k<4;k++) acc = __builtin_amdgcn_mfma_f32_16x16x32_bf16(af[k], ldf(bp + k*32), acc,0,0,0);
      #pragma unroll
      for (int r=0;r<4;r++) abuf[(q*4+r)*AB + cc] = f2b(acc[r]);
    }
  }
  __syncthreads();

  float res[4][4];
  {
    short8 aw[8];
    #pragma unroll
    for (int k=0;k<8;k++) aw[k] = ldf(abuf + l15*AB + k*32 + q*8);
    #pragma unroll
    for (int tt=0;tt<4;tt++){
      int cc = w*64 + tt*16 + l15;
      const unsigned short* bp = WnoT + (size_t)cc*256 + q*8;
      f32x4 acc = {0.f,0.f,0.f,0.f};
      #pragma unroll
      for (int k=0;k<8;k++) acc = __builtin_amdgcn_mfma_f32_16x16x32_bf16(aw[k], ldf(bp + k*32), acc,0,0,0);
      float bb = bno[cc];
      #pragma unroll
      for (int r=0;r<4;r++)
        res[tt][r] = nodes[(size_t)(b*128+n0+q*4+r)*256 + cc] + acc[r] + bb;
    }
  }
  #pragma unroll
  for (int r=0;r<4;r++){
    float ps = res[0][r]+res[1][r]+res[2][r]+res[3][r];
    float p2 = res[0][r]*res[0][r]+res[1][r]*res[1][r]+res[2][r]*res[2][r]+res[3][r]*res[3][r];
    ps += __shfl_xor(ps,1); ps += __shfl_xor(ps,2); ps += __shfl_xor(ps,4); ps += __shfl_xor(ps,8);
    p2 += __shfl_xor(p2,1); p2 += __shfl_xor(p2,2); p2 += __shfl_xor(p2,4); p2 += __shfl_xor(p2,8);
    if (l15 == 0){ redS[q*4+r][w] = ps; redQ[q*4+r][w] = p2; }
  }
  __syncthreads();
  if (t < 16){
    float s = redS[t][0]+redS[t][1]+redS[t][2]+redS[t][3];
    float s2 = redQ[t][0]+redQ[t][1]+redQ[t][2]+redQ[t][3];
    float m = s*(1.f/256);
    mrow[t] = m; irow[t] = rsqrtf(s2*(1.f/256) - m*m + 1e-5f);
  }
  __syncthreads();
  #pragma unroll
  for (int tt=0;tt<4;tt++){
    int cc = w*64 + tt*16 + l15;
    float mul = 1.f + cond[b*1024 + 512 + cc];
    float add = cond[b*1024 + 768 + cc];
    #pragma unroll
    for (int r=0;r<4;r++){
      int row = q*4+r;
      abuf[row*AB + cc] = f2b(lrelu((res[tt][r] - mrow[row])*irow[row]*mul + add));
    }
  }
  if (slice == 0){
    #pragma unroll
    for (int tt=0;tt<4;tt++){
      int cc = w*64 + tt*16 + l15;
      #pragma unroll
      for (int r=0;r<4;r++)
        nodes1ws[(size_t)(rg*16 + q*4+r)*256 + cc] = res[tt][r];
    }
  }
  __syncthreads();
  {
    short8 a2[8];
    #pragma unroll
    for (int k=0;k<8;k++) a2[k] = ldf(abuf + l15*AB + k*32 + q*8);
    #pragma unroll
    for (int tt=0;tt<4;tt++){
      int cc = slice*256 + w*64 + tt*16 + l15;
      const unsigned short* bp = Wn1T + (size_t)cc*256 + q*8;
      f32x4 acc = {0.f,0.f,0.f,0.f};
      #pragma unroll
      for (int k=0;k<8;k++) acc = __builtin_amdgcn_mfma_f32_16x16x32_bf16(a2[k], ldf(bp + k*32), acc,0,0,0);
      float bb = bn1[cc];
      #pragma unroll
      for (int r=0;r<4;r++)
        hiddenB[((size_t)rg*16 + q*4+r)*1024 + cc] = f2b(lrelu(acc[r] + bb));
    }
  }
}

// ---- nodeC (grid 128 = 32 rowgroups x 4 col-slices): mlp2 (K=1024) + residual ----
__global__ __launch_bounds__(256) void k_nodeC(
    const unsigned short* __restrict__ hiddenB, const float* __restrict__ nodes1ws,
    const unsigned short* __restrict__ Wn2T, const float* __restrict__ bn2,
    float* __restrict__ out_nodes){
  int t = threadIdx.x;
  int rg = blockIdx.x >> 2, cs = blockIdx.x & 3;
  int w = t >> 6, l15 = t & 15, q = (t & 63) >> 4;
  int cc = cs*64 + w*16 + l15;
  const unsigned short* ap = hiddenB + ((size_t)rg*16 + l15)*1024 + q*8;
  const unsigned short* bp = Wn2T + (size_t)cc*1024 + q*8;
  f32x4 acc = {0.f,0.f,0.f,0.f};
  #pragma unroll
  for (int k=0;k<32;k++)
    acc = __builtin_amdgcn_mfma_f32_16x16x32_bf16(ldf(ap + k*32), ldf(bp + k*32), acc,0,0,0);
  float bb = bn2[cc];
  #pragma unroll
  for (int r=0;r<4;r++){
    size_t row = (size_t)rg*16 + q*4 + r;
    out_nodes[row*256 + cc] = nodes1ws[row*256 + cc] + acc[r] + bb;
  }
}

extern "C" void kernel_launch(void* const* d_in, const int* in_sizes, int n_inp,
                              void* d_out, int out_size, void* d_ws, size_t ws_size,
                              hipStream_t stream){
  const float* nodes = (const float*)d_in[0];
  const float* edges = (const float*)d_in[1];
  const float* conds = (const float*)d_in[2];
  const float* Wc   = (const float*)d_in[3];
  const float* bc   = (const float*)d_in[4];
  const float* Wqkv = (const float*)d_in[5];
  const float* bqkv = (const float*)d_in[6];
  const float* Wss  = (const float*)d_in[7];
  const float* bss  = (const float*)d_in[8];
  const float* Wno  = (const float*)d_in[9];
  const float* bno  = (const float*)d_in[10];
  const float* Weo  = (const float*)d_in[11];
  const float* beo  = (const float*)d_in[12];
  const float* Wn1  = (const float*)d_in[13];
  const float* bn1  = (const float*)d_in[14];
  const float* Wn2  = (const float*)d_in[15];
  const float* bn2  = (const float*)d_in[16];
  const float* We1  = (const float*)d_in[17];
  const float* be1  = (const float*)d_in[18];
  const float* We2  = (const float*)d_in[19];
  const float* be2  = (const float*)d_in[20];

  float* ws       = (float*)d_ws;
  float* cond     = ws;                       // 4096
  float* qbuf     = cond + 4096;              // 131072
  float* kT       = qbuf + 131072;            // 131072
  float* logitsT  = kT + 131072;              // 524288
  float* nodes1ws = logitsT + 524288;         // 131072
  unsigned short* attnB   = (unsigned short*)(nodes1ws + 131072); // 524288 us
  unsigned short* vT      = attnB + 524288;                       // 131072 us
  unsigned short* hiddenB = vT + 131072;                          // 524288 us
  unsigned short* wbf     = hiddenB + 524288;                     // 917504 us

  unsigned short* WssT  = wbf;
  unsigned short* WeoT  = wbf + 65536;
  unsigned short* We1T  = wbf + 98304;
  unsigned short* We2T  = wbf + 114688;
  unsigned short* WqkvT = wbf + 131072;
  unsigned short* WnoT  = wbf + 327680;
  unsigned short* Wn1T  = wbf + 393216;
  unsigned short* Wn2T  = wbf + 655360;

  float* out_nodes = (float*)d_out;
  float* out_edges = out_nodes + 131072;

  k_setup<<<912, 256, 0, stream>>>(Wss, Weo, We1, We2, Wqkv, Wno, Wn1, Wn2,
                                   conds, Wc, bc, wbf, cond);
  k_nodeA<<<128, 256, 0, stream>>>(nodes, cond, WqkvT, bqkv, qbuf, kT, vT);
  k_edge<<<BB*NN*NN/64, 256, 0, stream>>>(edges, qbuf, kT, WssT, bss, WeoT, beo,
                                          We1T, be1, We2T, be2, logitsT, out_edges);
  k_attn<<<BB*NH*8, 256, 0, stream>>>(logitsT, attnB);
  k_nodeB<<<128, 256, 0, stream>>>(attnB, vT, nodes, cond, WnoT, bno, Wn1T, bn1,
                                   nodes1ws, hiddenB);
  k_nodeC<<<128, 256, 0, stream>>>(hiddenB, nodes1ws, Wn2T, bn2, out_nodes);
}